// Round 1
// baseline (1699.109 us; speedup 1.0000x reference)
//
#include <hip/hip_runtime.h>
#include <stdint.h>

#define NEG_INF (-__builtin_inff())

namespace {
constexpr int kB   = 2;
constexpr int kT   = 1024;
constexpr int kE   = 2048;
constexpr int kH   = 32;
constexpr int kD   = 64;
constexpr int kBH  = kB * kH;   // 64
constexpr int kTok = kB * kT;   // 2048
}

// ---------------- reduction helpers ----------------
__device__ __forceinline__ float waveReduceMax(float v) {
#pragma unroll
  for (int o = 32; o > 0; o >>= 1) v = fmaxf(v, __shfl_down(v, o, 64));
  return v;
}
__device__ __forceinline__ float waveReduceSum(float v) {
#pragma unroll
  for (int o = 32; o > 0; o >>= 1) v += __shfl_down(v, o, 64);
  return v;
}
// 256-thread block max; includes two syncthreads (uses r4[4] shared scratch)
__device__ __forceinline__ float blockMax256(float v, float* r4) {
  const int tid = threadIdx.x;
  float wm = waveReduceMax(v);
  if ((tid & 63) == 0) r4[tid >> 6] = wm;
  __syncthreads();
  float bm = fmaxf(fmaxf(r4[0], r4[1]), fmaxf(r4[2], r4[3]));
  __syncthreads();
  return bm;
}

// ---------------- quantization kernels ----------------
// per-row (length kE) absmax -> int8 quant, scale = max(am,1e-5)/127
__global__ __launch_bounds__(256) void k_rowquant_i8(const float* __restrict__ X,
                                                     int8_t* __restrict__ Xq,
                                                     float* __restrict__ S) {
  const int row = blockIdx.x;
  const int tid = threadIdx.x;
  const float* x = X + (size_t)row * kE;
  __shared__ float r4[4];
  float am = 0.f;
#pragma unroll
  for (int it = 0; it < 2; ++it) {
    const float4 v = *reinterpret_cast<const float4*>(x + (size_t)(it * 256 + tid) * 4);
    am = fmaxf(am, fmaxf(fmaxf(fabsf(v.x), fabsf(v.y)), fmaxf(fabsf(v.z), fabsf(v.w))));
  }
  const float bm = blockMax256(am, r4);
  const float s = fmaxf(bm, 1e-5f) / 127.f;
  int8_t* xq = Xq + (size_t)row * kE;
#pragma unroll
  for (int it = 0; it < 2; ++it) {
    const int i = (it * 256 + tid) * 4;
    const float4 v = *reinterpret_cast<const float4*>(x + i);
    char4 q;
    q.x = (char)(int)rintf(v.x / s);
    q.y = (char)(int)rintf(v.y / s);
    q.z = (char)(int)rintf(v.z / s);
    q.w = (char)(int)rintf(v.w / s);
    *reinterpret_cast<char4*>(xq + i) = q;
  }
  if (tid == 0) S[row] = s;
}

// q: per-token 8-bit requant in place, then * 0.125 (D^-0.5)
__global__ __launch_bounds__(256) void k_qquant(float* __restrict__ Qb) {
  const int row = blockIdx.x;
  const int tid = threadIdx.x;
  float* x = Qb + (size_t)row * kE;
  __shared__ float r4[4];
  float am = 0.f;
#pragma unroll
  for (int it = 0; it < 2; ++it) {
    const float4 v = *reinterpret_cast<const float4*>(x + (size_t)(it * 256 + tid) * 4);
    am = fmaxf(am, fmaxf(fmaxf(fabsf(v.x), fabsf(v.y)), fmaxf(fabsf(v.z), fabsf(v.w))));
  }
  const float bm = blockMax256(am, r4);
  const float s = fmaxf(bm, 1e-5f) / 127.f;
#pragma unroll
  for (int it = 0; it < 2; ++it) {
    const int i = (it * 256 + tid) * 4;
    float4 v = *reinterpret_cast<const float4*>(x + i);
    v.x = rintf(v.x / s) * s * 0.125f;
    v.y = rintf(v.y / s) * s * 0.125f;
    v.z = rintf(v.z / s) * s * 0.125f;
    v.w = rintf(v.w / s) * s * 0.125f;
    *reinterpret_cast<float4*>(x + i) = v;
  }
}

// k scales: s4[row]=max(am,1e-5)/7 ; for batch 0 rows: smix[t]=max(am/127,1e-5)
__global__ __launch_bounds__(256) void k_kscale(const float* __restrict__ Kb,
                                                float* __restrict__ s4,
                                                float* __restrict__ smix) {
  const int row = blockIdx.x;
  const int tid = threadIdx.x;
  const float* x = Kb + (size_t)row * kE;
  __shared__ float r4[4];
  float am = 0.f;
#pragma unroll
  for (int it = 0; it < 2; ++it) {
    const float4 v = *reinterpret_cast<const float4*>(x + (size_t)(it * 256 + tid) * 4);
    am = fmaxf(am, fmaxf(fmaxf(fabsf(v.x), fabsf(v.y)), fmaxf(fabsf(v.z), fabsf(v.w))));
  }
  const float bm = blockMax256(am, r4);
  if (tid == 0) {
    s4[row] = fmaxf(bm, 1e-5f) / 7.f;
    if (row < kT) smix[row] = fmaxf(bm / 127.f, 1e-5f);
  }
}

__global__ void k_init(unsigned* vmax) {
  if (threadIdx.x == 0 && blockIdx.x == 0) *vmax = 0u;
}

__global__ __launch_bounds__(256) void k_vabsmax(const float* __restrict__ Vb,
                                                 unsigned* __restrict__ vmax) {
  const int row = blockIdx.x;
  const int tid = threadIdx.x;
  const float* x = Vb + (size_t)row * kE;
  __shared__ float r4[4];
  float am = 0.f;
#pragma unroll
  for (int it = 0; it < 2; ++it) {
    const float4 v = *reinterpret_cast<const float4*>(x + (size_t)(it * 256 + tid) * 4);
    am = fmaxf(am, fmaxf(fmaxf(fabsf(v.x), fabsf(v.y)), fmaxf(fabsf(v.z), fabsf(v.w))));
  }
  const float bm = blockMax256(am, r4);
  if (tid == 0) atomicMax(vmax, __float_as_uint(bm));  // bm >= 0: uint order == float order
}

// k mixed requant in place. 8 elems / thread, chunks never cross a row.
__global__ __launch_bounds__(256) void k_kquant(float* __restrict__ Kb,
                                                const float* __restrict__ s4,
                                                const float* __restrict__ smix,
                                                const int* __restrict__ sel) {
  const int idx = blockIdx.x * 256 + threadIdx.x;
  const size_t base = (size_t)idx * 8;
  const int row = (int)(base >> 11);
  const int t = row & (kT - 1);
  const float s = sel[t] ? smix[t] : s4[row];
  float4 a = *reinterpret_cast<float4*>(Kb + base);
  float4 b = *reinterpret_cast<float4*>(Kb + base + 4);
  a.x = rintf(a.x / s) * s; a.y = rintf(a.y / s) * s;
  a.z = rintf(a.z / s) * s; a.w = rintf(a.w / s) * s;
  b.x = rintf(b.x / s) * s; b.y = rintf(b.y / s) * s;
  b.z = rintf(b.z / s) * s; b.w = rintf(b.w / s) * s;
  *reinterpret_cast<float4*>(Kb + base) = a;
  *reinterpret_cast<float4*>(Kb + base + 4) = b;
}

__global__ __launch_bounds__(256) void k_vquant(float* __restrict__ Vb,
                                                const unsigned* __restrict__ vmax) {
  const float sv = fmaxf(__uint_as_float(*vmax), 1e-5f) / 7.f;
  const int idx = blockIdx.x * 256 + threadIdx.x;
  const size_t base = (size_t)idx * 8;
  float4 a = *reinterpret_cast<float4*>(Vb + base);
  float4 b = *reinterpret_cast<float4*>(Vb + base + 4);
  a.x = rintf(a.x / sv) * sv; a.y = rintf(a.y / sv) * sv;
  a.z = rintf(a.z / sv) * sv; a.w = rintf(a.w / sv) * sv;
  b.x = rintf(b.x / sv) * sv; b.y = rintf(b.y / sv) * sv;
  b.z = rintf(b.z / sv) * sv; b.w = rintf(b.w / sv) * sv;
  *reinterpret_cast<float4*>(Vb + base) = a;
  *reinterpret_cast<float4*>(Vb + base + 4) = b;
}

// ---------------- int8-input GEMM: Y = (Ai8*sa) @ (Bi8*sb)^T + bias ----------------
// M=N=K=2048; A (M,K) int8 row-major, Bw (N,K) int8 row-major.
__global__ __launch_bounds__(256) void k_gemm_q8(const int8_t* __restrict__ A,
                                                 const float* __restrict__ sa,
                                                 const int8_t* __restrict__ Bw,
                                                 const float* __restrict__ sw,
                                                 const float* __restrict__ bias,
                                                 float* __restrict__ Y) {
  __shared__ float As[16][128];
  __shared__ float Bs[16][128];
  const int tid = threadIdx.x;
  const int m0 = blockIdx.y * 128, n0 = blockIdx.x * 128;
  const int tr = tid >> 4, tc = tid & 15;
  float acc[8][8];
#pragma unroll
  for (int r = 0; r < 8; ++r)
#pragma unroll
    for (int c = 0; c < 8; ++c) acc[r][c] = 0.f;

  const int lrow = tid >> 1, seg = (tid & 1) << 3;
  const int8_t* aptr = A + (size_t)(m0 + lrow) * kE + seg;
  const int8_t* bptr = Bw + (size_t)(n0 + lrow) * kE + seg;

  for (int k0 = 0; k0 < kE; k0 += 16) {
    const uint64_t ra = *reinterpret_cast<const uint64_t*>(aptr + k0);
    const uint64_t rb = *reinterpret_cast<const uint64_t*>(bptr + k0);
#pragma unroll
    for (int i = 0; i < 8; ++i) {
      As[seg + i][lrow] = (float)(int)(int8_t)(ra >> (i * 8));
      Bs[seg + i][lrow] = (float)(int)(int8_t)(rb >> (i * 8));
    }
    __syncthreads();
#pragma unroll
    for (int k = 0; k < 16; ++k) {
      float a[8], b[8];
      *reinterpret_cast<float4*>(&a[0]) = *reinterpret_cast<const float4*>(&As[k][tr * 8]);
      *reinterpret_cast<float4*>(&a[4]) = *reinterpret_cast<const float4*>(&As[k][tr * 8 + 4]);
      *reinterpret_cast<float4*>(&b[0]) = *reinterpret_cast<const float4*>(&Bs[k][tc * 8]);
      *reinterpret_cast<float4*>(&b[4]) = *reinterpret_cast<const float4*>(&Bs[k][tc * 8 + 4]);
#pragma unroll
      for (int r = 0; r < 8; ++r)
#pragma unroll
        for (int c = 0; c < 8; ++c) acc[r][c] = fmaf(a[r], b[c], acc[r][c]);
    }
    __syncthreads();
  }
  float swv[8], bvv[8];
#pragma unroll
  for (int c = 0; c < 8; ++c) {
    swv[c] = sw[n0 + tc * 8 + c];
    bvv[c] = bias[n0 + tc * 8 + c];
  }
#pragma unroll
  for (int r = 0; r < 8; ++r) {
    const int m = m0 + tr * 8 + r;
    const float sm = sa[m];
    float4 o0, o1;
    o0.x = acc[r][0] * sm * swv[0] + bvv[0];
    o0.y = acc[r][1] * sm * swv[1] + bvv[1];
    o0.z = acc[r][2] * sm * swv[2] + bvv[2];
    o0.w = acc[r][3] * sm * swv[3] + bvv[3];
    o1.x = acc[r][4] * sm * swv[4] + bvv[4];
    o1.y = acc[r][5] * sm * swv[5] + bvv[5];
    o1.z = acc[r][6] * sm * swv[6] + bvv[6];
    o1.w = acc[r][7] * sm * swv[7] + bvv[7];
    float* yp = Y + (size_t)m * kE + n0 + tc * 8;
    *reinterpret_cast<float4*>(yp) = o0;
    *reinterpret_cast<float4*>(yp + 4) = o1;
  }
}

// ---------------- attention pass 1: column prob sums ----------------
// grid (16 row-tiles, 64 heads); writes accPart[bh*16+rt][1024]
__global__ __launch_bounds__(256) void k_attn1(const float* __restrict__ Qb,
                                               const float* __restrict__ Kb,
                                               float* __restrict__ accPart) {
  const int rt = blockIdx.x;
  const int bh = blockIdx.y;
  const int b = bh >> 5, h = bh & 31;
  const int tid = threadIdx.x;
  const int tr = tid >> 4, tc = tid & 15;

  __shared__ float Qs[64][68];
  __shared__ float Ks[64][68];
  __shared__ float accL[1024];
  __shared__ float red[64][17];
  __shared__ float mrow[64], lrow[64], mns[64];

  for (int i = tid; i < 1024; i += 256) accL[i] = 0.f;
  if (tid < 64) { mrow[tid] = NEG_INF; lrow[tid] = 0.f; }

  const size_t qbase = ((size_t)(b * kT + rt * 64)) * kE + h * kD;
#pragma unroll
  for (int i = 0; i < 16; ++i) {
    const int e = i * 256 + tid;
    Qs[e & 63][e >> 6] = Qb[qbase + (size_t)(e >> 6) * kE + (e & 63)];
  }
  __syncthreads();

  // ---- pass 1: running max / sum ----
  for (int kt = 0; kt <= rt; ++kt) {
    const size_t kbase = ((size_t)(b * kT + kt * 64)) * kE + h * kD;
#pragma unroll
    for (int i = 0; i < 16; ++i) {
      const int e = i * 256 + tid;
      Ks[e & 63][e >> 6] = Kb[kbase + (size_t)(e >> 6) * kE + (e & 63)];
    }
    __syncthreads();

    float s[4][4];
#pragma unroll
    for (int r = 0; r < 4; ++r)
#pragma unroll
      for (int c = 0; c < 4; ++c) s[r][c] = 0.f;
#pragma unroll 8
    for (int d = 0; d < 64; ++d) {
      const float4 qv = *reinterpret_cast<const float4*>(&Qs[d][tr * 4]);
      const float4 kv = *reinterpret_cast<const float4*>(&Ks[d][tc * 4]);
      const float qa[4] = {qv.x, qv.y, qv.z, qv.w};
      const float ka[4] = {kv.x, kv.y, kv.z, kv.w};
#pragma unroll
      for (int r = 0; r < 4; ++r)
#pragma unroll
        for (int c = 0; c < 4; ++c) s[r][c] = fmaf(qa[r], ka[c], s[r][c]);
    }
#pragma unroll
    for (int r = 0; r < 4; ++r) {
      const int t = rt * 64 + tr * 4 + r;
      float pm = NEG_INF;
#pragma unroll
      for (int c = 0; c < 4; ++c) {
        const int j = kt * 64 + tc * 4 + c;
        if (j > t) s[r][c] = NEG_INF;
        pm = fmaxf(pm, s[r][c]);
      }
      red[tr * 4 + r][tc] = pm;
    }
    __syncthreads();
    if (tid < 64) {
      float tm = red[tid][0];
#pragma unroll
      for (int c = 1; c < 16; ++c) tm = fmaxf(tm, red[tid][c]);
      const float mo = mrow[tid];
      const float mn = fmaxf(mo, tm);
      mns[tid] = mn;
      lrow[tid] *= expf(mo - mn);
      mrow[tid] = mn;
    }
    __syncthreads();
#pragma unroll
    for (int r = 0; r < 4; ++r) {
      const float mn = mns[tr * 4 + r];
      float ps = 0.f;
#pragma unroll
      for (int c = 0; c < 4; ++c) ps += expf(s[r][c] - mn);  // exp(-inf)=0
      red[tr * 4 + r][tc] = ps;
    }
    __syncthreads();
    if (tid < 64) {
      float t = 0.f;
#pragma unroll
      for (int c = 0; c < 16; ++c) t += red[tid][c];
      lrow[tid] += t;
    }
    __syncthreads();
  }

  if (tid < 64) lrow[tid] = 1.f / lrow[tid];
  __syncthreads();

  // ---- pass 2: accumulate normalized probabilities per column ----
  for (int kt = 0; kt <= rt; ++kt) {
    const size_t kbase = ((size_t)(b * kT + kt * 64)) * kE + h * kD;
#pragma unroll
    for (int i = 0; i < 16; ++i) {
      const int e = i * 256 + tid;
      Ks[e & 63][e >> 6] = Kb[kbase + (size_t)(e >> 6) * kE + (e & 63)];
    }
    __syncthreads();

    float s[4][4];
#pragma unroll
    for (int r = 0; r < 4; ++r)
#pragma unroll
      for (int c = 0; c < 4; ++c) s[r][c] = 0.f;
#pragma unroll 8
    for (int d = 0; d < 64; ++d) {
      const float4 qv = *reinterpret_cast<const float4*>(&Qs[d][tr * 4]);
      const float4 kv = *reinterpret_cast<const float4*>(&Ks[d][tc * 4]);
      const float qa[4] = {qv.x, qv.y, qv.z, qv.w};
      const float ka[4] = {kv.x, kv.y, kv.z, kv.w};
#pragma unroll
      for (int r = 0; r < 4; ++r)
#pragma unroll
        for (int c = 0; c < 4; ++c) s[r][c] = fmaf(qa[r], ka[c], s[r][c]);
    }
    float colp[4] = {0.f, 0.f, 0.f, 0.f};
#pragma unroll
    for (int r = 0; r < 4; ++r) {
      const int t = rt * 64 + tr * 4 + r;
      const float mn = mrow[tr * 4 + r];
      const float il = lrow[tr * 4 + r];
#pragma unroll
      for (int c = 0; c < 4; ++c) {
        const int j = kt * 64 + tc * 4 + c;
        const float p = (j <= t) ? expf(s[r][c] - mn) * il : 0.f;
        colp[c] += p;
      }
    }
#pragma unroll
    for (int c = 0; c < 4; ++c) red[tc * 4 + c][tr] = colp[c];
    __syncthreads();
    if (tid < 64) {
      float t = 0.f;
#pragma unroll
      for (int i = 0; i < 16; ++i) t += red[tid][i];
      accL[kt * 64 + tid] += t;
    }
    __syncthreads();
  }

  float* op = accPart + ((size_t)(bh * 16 + rt)) * 1024;
  for (int i = tid; i < 1024; i += 256) op[i] = accL[i];
}

// reduce accPart over 1024 blocks, apply /(T-j)/64
__global__ __launch_bounds__(256) void k_accreduce(const float* __restrict__ part,
                                                   float* __restrict__ acc) {
  const int j = blockIdx.x;
  const int tid = threadIdx.x;
  float s = 0.f;
  for (int p = tid; p < 1024; p += 256) s += part[(size_t)p * 1024 + j];
  __shared__ float r4[4];
  const float ws = waveReduceSum(s);
  if ((tid & 63) == 0) r4[tid >> 6] = ws;
  __syncthreads();
  if (tid == 0) {
    const float t = r4[0] + r4[1] + r4[2] + r4[3];
    acc[j] = t / (float)(kT - j) / 64.f;
  }
}

// per-group (256 wide) top-128 selection mask; lax.top_k tie-break = lower index
__global__ __launch_bounds__(256) void k_topk(const float* __restrict__ acc,
                                              int* __restrict__ sel) {
  const int g = blockIdx.x;
  const int i = threadIdx.x;
  __shared__ float v[256];
  const float vi = acc[g * 256 + i];
  v[i] = vi;
  __syncthreads();
  int rank = 0;
  for (int j = 0; j < 256; ++j) {
    const float vj = v[j];
    rank += (vj > vi) || (vj == vi && j < i);
  }
  sel[g * 256 + i] = (rank < 128) ? 1 : 0;
}

// ---------------- attention pass 2: flash with PV ----------------
__global__ __launch_bounds__(256) void k_attn2(const float* __restrict__ Qb,
                                               const float* __restrict__ Kb,
                                               const float* __restrict__ Vb,
                                               float* __restrict__ Cb) {
  const int rt = blockIdx.x;
  const int bh = blockIdx.y;
  const int b = bh >> 5, h = bh & 31;
  const int tid = threadIdx.x;
  const int tr = tid >> 4, tc = tid & 15;

  __shared__ float Qs[64][68];
  __shared__ float KPs[64][68];  // K tile ([d][j]) then reused as P tile ([j][row])
  __shared__ float Vs[64][68];   // [j][d]
  __shared__ float red[64][17];
  __shared__ float mrow[64], lrow[64], fr[64], mns[64];

  if (tid < 64) { mrow[tid] = NEG_INF; lrow[tid] = 0.f; }
  const size_t qbase = ((size_t)(b * kT + rt * 64)) * kE + h * kD;
#pragma unroll
  for (int i = 0; i < 16; ++i) {
    const int e = i * 256 + tid;
    Qs[e & 63][e >> 6] = Qb[qbase + (size_t)(e >> 6) * kE + (e & 63)];
  }
  float out[4][4];
#pragma unroll
  for (int r = 0; r < 4; ++r)
#pragma unroll
    for (int c = 0; c < 4; ++c) out[r][c] = 0.f;
  __syncthreads();

  for (int kt = 0; kt <= rt; ++kt) {
    const size_t kbase = ((size_t)(b * kT + kt * 64)) * kE + h * kD;
#pragma unroll
    for (int i = 0; i < 16; ++i) {
      const int e = i * 256 + tid;
      const int j2 = e >> 6, d = e & 63;
      const size_t g = kbase + (size_t)j2 * kE + d;
      KPs[d][j2] = Kb[g];
      Vs[j2][d] = Vb[g];
    }
    __syncthreads();  // (1)

    float s[4][4];
#pragma unroll
    for (int r = 0; r < 4; ++r)
#pragma unroll
      for (int c = 0; c < 4; ++c) s[r][c] = 0.f;
#pragma unroll 8
    for (int d = 0; d < 64; ++d) {
      const float4 qv = *reinterpret_cast<const float4*>(&Qs[d][tr * 4]);
      const float4 kv = *reinterpret_cast<const float4*>(&KPs[d][tc * 4]);
      const float qa[4] = {qv.x, qv.y, qv.z, qv.w};
      const float ka[4] = {kv.x, kv.y, kv.z, kv.w};
#pragma unroll
      for (int r = 0; r < 4; ++r)
#pragma unroll
        for (int c = 0; c < 4; ++c) s[r][c] = fmaf(qa[r], ka[c], s[r][c]);
    }
#pragma unroll
    for (int r = 0; r < 4; ++r) {
      const int t = rt * 64 + tr * 4 + r;
      float pm = NEG_INF;
#pragma unroll
      for (int c = 0; c < 4; ++c) {
        const int j = kt * 64 + tc * 4 + c;
        if (j > t) s[r][c] = NEG_INF;
        pm = fmaxf(pm, s[r][c]);
      }
      red[tr * 4 + r][tc] = pm;
    }
    __syncthreads();  // (2)
    if (tid < 64) {
      float tm = red[tid][0];
#pragma unroll
      for (int c = 1; c < 16; ++c) tm = fmaxf(tm, red[tid][c]);
      const float mo = mrow[tid];
      const float mn = fmaxf(mo, tm);
      mns[tid] = mn;
      fr[tid] = expf(mo - mn);
      mrow[tid] = mn;
    }
    __syncthreads();  // (3) -- K reads all done; safe to overwrite KPs with P
#pragma unroll
    for (int r = 0; r < 4; ++r) {
      const int row = tr * 4 + r;
      const float mn = mns[row];
      const float f = fr[row];
      float ps = 0.f;
#pragma unroll
      for (int c = 0; c < 4; ++c) {
        const float p = expf(s[r][c] - mn);  // masked -> 0
        KPs[tc * 4 + c][row] = p;
        ps += p;
        out[r][c] *= f;  // rescale each O element exactly once per tile
      }
      red[row][tc] = ps;
    }
    __syncthreads();  // (4)
    if (tid < 64) {
      float t = 0.f;
#pragma unroll
      for (int i = 0; i < 16; ++i) t += red[tid][i];
      lrow[tid] = lrow[tid] * fr[tid] + t;
    }
#pragma unroll 8
    for (int j = 0; j < 64; ++j) {
      const float4 pv = *reinterpret_cast<const float4*>(&KPs[j][tr * 4]);
      const float4 vv = *reinterpret_cast<const float4*>(&Vs[j][tc * 4]);
      const float pa[4] = {pv.x, pv.y, pv.z, pv.w};
      const float va[4] = {vv.x, vv.y, vv.z, vv.w};
#pragma unroll
      for (int r = 0; r < 4; ++r)
#pragma unroll
        for (int c = 0; c < 4; ++c) out[r][c] = fmaf(pa[r], va[c], out[r][c]);
    }
    __syncthreads();  // (5)
  }

#pragma unroll
  for (int r = 0; r < 4; ++r) {
    const int row = tr * 4 + r;
    const float il = 1.f / lrow[row];
    float4 o;
    o.x = out[r][0] * il;
    o.y = out[r][1] * il;
    o.z = out[r][2] * il;
    o.w = out[r][3] * il;
    *reinterpret_cast<float4*>(
        &Cb[((size_t)(b * kT + rt * 64 + row)) * kE + h * kD + tc * 4]) = o;
  }
}

// ---------------- launcher ----------------
extern "C" void kernel_launch(void* const* d_in, const int* in_sizes, int n_in,
                              void* d_out, int out_size, void* d_ws, size_t ws_size,
                              hipStream_t stream) {
  (void)in_sizes; (void)n_in; (void)out_size; (void)ws_size;
  const float* hs = (const float*)d_in[0];
  // d_in[1] attention_mask: exactly causal -> applied analytically
  const float* Wq = (const float*)d_in[2];
  const float* bq = (const float*)d_in[3];
  const float* Wk = (const float*)d_in[4];
  const float* bk = (const float*)d_in[5];
  const float* Wv = (const float*)d_in[6];
  const float* bv = (const float*)d_in[7];
  const float* Wo = (const float*)d_in[8];
  const float* bo = (const float*)d_in[9];
  float* out = (float*)d_out;

  char* p = (char*)d_ws;
  auto take = [&](size_t bytes) {
    char* r = p;
    p += (bytes + 255) & ~(size_t)255;
    return r;
  };
  float* qb   = (float*)take((size_t)kTok * kE * 4);
  float* kb   = (float*)take((size_t)kTok * kE * 4);
  float* vb   = (float*)take((size_t)kTok * kE * 4);
  float* ctxb = (float*)take((size_t)kTok * kE * 4);
  float* accPart = ctxb;  // 4 MB, consumed before ctxb is written
  int8_t* xq  = (int8_t*)take((size_t)kTok * kE);
  int8_t* wqq = (int8_t*)take((size_t)kE * kE);
  int8_t* wkq = (int8_t*)take((size_t)kE * kE);
  int8_t* wvq = (int8_t*)take((size_t)kE * kE);
  int8_t* woq = (int8_t*)take((size_t)kE * kE);
  float* sX   = (float*)take(kTok * 4);
  float* sWq  = (float*)take(kE * 4);
  float* sWk  = (float*)take(kE * 4);
  float* sWv  = (float*)take(kE * 4);
  float* sWo  = (float*)take(kE * 4);
  float* sC   = (float*)take(kTok * 4);
  float* s4v  = (float*)take(kTok * 4);
  float* smix = (float*)take(kT * 4);
  float* accv = (float*)take(kT * 4);
  int* sel    = (int*)take(kT * 4);
  unsigned* vmax = (unsigned*)take(256);
  int8_t* cq = xq;  // reuse: xq is dead after the three projections

  // 1) quantize activations + weights
  k_rowquant_i8<<<kTok, 256, 0, stream>>>(hs, xq, sX);
  k_rowquant_i8<<<kE, 256, 0, stream>>>(Wq, wqq, sWq);
  k_rowquant_i8<<<kE, 256, 0, stream>>>(Wk, wkq, sWk);
  k_rowquant_i8<<<kE, 256, 0, stream>>>(Wv, wvq, sWv);
  k_rowquant_i8<<<kE, 256, 0, stream>>>(Wo, woq, sWo);

  // 2) projections
  dim3 gg(16, 16);
  k_gemm_q8<<<gg, 256, 0, stream>>>(xq, sX, wqq, sWq, bq, qb);
  k_gemm_q8<<<gg, 256, 0, stream>>>(xq, sX, wkq, sWk, bk, kb);
  k_gemm_q8<<<gg, 256, 0, stream>>>(xq, sX, wvq, sWv, bv, vb);

  // 3) q requant * scaling
  k_qquant<<<kTok, 256, 0, stream>>>(qb);

  // 4) attention pass 1 -> column prob sums -> top-k mask
  dim3 ga(16, kBH);
  k_attn1<<<ga, 256, 0, stream>>>(qb, kb, accPart);
  k_accreduce<<<1024, 256, 0, stream>>>(accPart, accv);
  k_topk<<<4, 256, 0, stream>>>(accv, sel);

  // 5) k / v quantization
  k_kscale<<<kTok, 256, 0, stream>>>(kb, s4v, smix);
  k_init<<<1, 64, 0, stream>>>(vmax);
  k_vabsmax<<<kTok, 256, 0, stream>>>(vb, vmax);
  k_kquant<<<2048, 256, 0, stream>>>(kb, s4v, smix, sel);
  k_vquant<<<2048, 256, 0, stream>>>(vb, vmax);

  // 6) attention pass 2
  k_attn2<<<ga, 256, 0, stream>>>(qb, kb, vb, ctxb);

  // 7) output projection
  k_rowquant_i8<<<kTok, 256, 0, stream>>>(ctxb, cq, sC);
  k_gemm_q8<<<gg, 256, 0, stream>>>(cq, sC, woq, sWo, bo, out);
}

// Round 2
// 455.318 us; speedup vs baseline: 3.7317x; 3.7317x over previous
//
#include <hip/hip_runtime.h>
#include <stdint.h>

#define NEG_INF (-__builtin_inff())

namespace {
constexpr int kT   = 1024;
constexpr int kE   = 2048;
}

using bf16x8 = __attribute__((ext_vector_type(8))) short;
using f32x4  = __attribute__((ext_vector_type(4))) float;
using i32x4  = __attribute__((ext_vector_type(4))) int;

#define MFMA_BF16(a, b, c) __builtin_amdgcn_mfma_f32_16x16x32_bf16((a), (b), (c), 0, 0, 0)
#define MFMA_I8(a, b, c)   __builtin_amdgcn_mfma_i32_16x16x64_i8((a), (b), (c), 0, 0, 0)

// ---------------- small helpers ----------------
__device__ __forceinline__ void gload16(const void* g, void* l) {
  __builtin_amdgcn_global_load_lds((const __attribute__((address_space(1))) unsigned*)g,
                                   (__attribute__((address_space(3))) unsigned*)l, 16, 0, 0);
}
__device__ __forceinline__ unsigned bfr(float x) {  // f32 -> bf16 bits (RNE)
  unsigned u = __float_as_uint(x);
  return (u + 0x7FFFu + ((u >> 16) & 1u)) >> 16;
}
__device__ __forceinline__ float bf2f(unsigned h) { return __uint_as_float(h << 16); }
__device__ __forceinline__ unsigned pk2(float a, float b) { return bfr(a) | (bfr(b) << 16); }

__device__ __forceinline__ float waveReduceMax(float v) {
#pragma unroll
  for (int o = 32; o > 0; o >>= 1) v = fmaxf(v, __shfl_down(v, o, 64));
  return v;
}
__device__ __forceinline__ float waveReduceSum(float v) {
#pragma unroll
  for (int o = 32; o > 0; o >>= 1) v += __shfl_down(v, o, 64);
  return v;
}
__device__ __forceinline__ float blockMax256(float v, float* r4) {
  const int tid = threadIdx.x;
  float wm = waveReduceMax(v);
  if ((tid & 63) == 0) r4[tid >> 6] = wm;
  __syncthreads();
  float bm = fmaxf(fmaxf(r4[0], r4[1]), fmaxf(r4[2], r4[3]));
  __syncthreads();
  return bm;
}

// ---------------- quantization kernels ----------------
__global__ __launch_bounds__(256) void k_rowquant_i8(const float* __restrict__ X,
                                                     int8_t* __restrict__ Xq,
                                                     float* __restrict__ S) {
  const int row = blockIdx.x;
  const int tid = threadIdx.x;
  const float* x = X + (size_t)row * kE;
  __shared__ float r4[4];
  float am = 0.f;
#pragma unroll
  for (int it = 0; it < 2; ++it) {
    const float4 v = *reinterpret_cast<const float4*>(x + (size_t)(it * 256 + tid) * 4);
    am = fmaxf(am, fmaxf(fmaxf(fabsf(v.x), fabsf(v.y)), fmaxf(fabsf(v.z), fabsf(v.w))));
  }
  const float bm = blockMax256(am, r4);
  const float s = fmaxf(bm, 1e-5f) / 127.f;
  int8_t* xq = Xq + (size_t)row * kE;
#pragma unroll
  for (int it = 0; it < 2; ++it) {
    const int i = (it * 256 + tid) * 4;
    const float4 v = *reinterpret_cast<const float4*>(x + i);
    char4 q;
    q.x = (char)(int)rintf(v.x / s);
    q.y = (char)(int)rintf(v.y / s);
    q.z = (char)(int)rintf(v.z / s);
    q.w = (char)(int)rintf(v.w / s);
    *reinterpret_cast<char4*>(xq + i) = q;
  }
  if (tid == 0) S[row] = s;
}

// q fp32 -> int codes as bf16 (exact), sqg = s * D^-0.5
__global__ __launch_bounds__(256) void k_q2int(const float* __restrict__ Qb,
                                               short* __restrict__ qi,
                                               float* __restrict__ sqg) {
  const int row = blockIdx.x;
  const int tid = threadIdx.x;
  const float* x = Qb + (size_t)row * kE;
  __shared__ float r4[4];
  float am = 0.f;
  float4 v[2];
#pragma unroll
  for (int it = 0; it < 2; ++it) {
    v[it] = *reinterpret_cast<const float4*>(x + (size_t)(it * 256 + tid) * 4);
    am = fmaxf(am, fmaxf(fmaxf(fabsf(v[it].x), fabsf(v[it].y)), fmaxf(fabsf(v[it].z), fabsf(v[it].w))));
  }
  const float bm = blockMax256(am, r4);
  const float s = fmaxf(bm, 1e-5f) / 127.f;
#pragma unroll
  for (int it = 0; it < 2; ++it) {
    const int i = (it * 256 + tid) * 4;
    short4 q;
    q.x = (short)bfr(rintf(v[it].x / s));
    q.y = (short)bfr(rintf(v[it].y / s));
    q.z = (short)bfr(rintf(v[it].z / s));
    q.w = (short)bfr(rintf(v[it].w / s));
    *reinterpret_cast<short4*>(qi + (size_t)row * kE + i) = q;
  }
  if (tid == 0) sqg[row] = s * 0.125f;
}

// k fp32 -> hi/lo bf16 split
__global__ __launch_bounds__(256) void k_ksplit(const float* __restrict__ Kb,
                                                short* __restrict__ khi,
                                                short* __restrict__ klo) {
  const int row = blockIdx.x;
  const int tid = threadIdx.x;
  const float* x = Kb + (size_t)row * kE;
#pragma unroll
  for (int it = 0; it < 2; ++it) {
    const int i = (it * 256 + tid) * 4;
    const float4 v = *reinterpret_cast<const float4*>(x + i);
    short4 h, l;
    unsigned hb;
    hb = bfr(v.x); h.x = (short)hb; l.x = (short)bfr(v.x - bf2f(hb));
    hb = bfr(v.y); h.y = (short)hb; l.y = (short)bfr(v.y - bf2f(hb));
    hb = bfr(v.z); h.z = (short)hb; l.z = (short)bfr(v.z - bf2f(hb));
    hb = bfr(v.w); h.w = (short)hb; l.w = (short)bfr(v.w - bf2f(hb));
    *reinterpret_cast<short4*>(khi + (size_t)row * kE + i) = h;
    *reinterpret_cast<short4*>(klo + (size_t)row * kE + i) = l;
  }
}

__global__ __launch_bounds__(256) void k_kscale(const float* __restrict__ Kb,
                                                float* __restrict__ s4,
                                                float* __restrict__ smix) {
  const int row = blockIdx.x;
  const int tid = threadIdx.x;
  const float* x = Kb + (size_t)row * kE;
  __shared__ float r4[4];
  float am = 0.f;
#pragma unroll
  for (int it = 0; it < 2; ++it) {
    const float4 v = *reinterpret_cast<const float4*>(x + (size_t)(it * 256 + tid) * 4);
    am = fmaxf(am, fmaxf(fmaxf(fabsf(v.x), fabsf(v.y)), fmaxf(fabsf(v.z), fabsf(v.w))));
  }
  const float bm = blockMax256(am, r4);
  if (tid == 0) {
    s4[row] = fmaxf(bm, 1e-5f) / 7.f;
    if (row < kT) smix[row] = fmaxf(bm / 127.f, 1e-5f);
  }
}

__global__ void k_init(unsigned* vmax) {
  if (threadIdx.x == 0 && blockIdx.x == 0) *vmax = 0u;
}

__global__ __launch_bounds__(256) void k_vabsmax(const float* __restrict__ Vb,
                                                 unsigned* __restrict__ vmax) {
  const int row = blockIdx.x;
  const int tid = threadIdx.x;
  const float* x = Vb + (size_t)row * kE;
  __shared__ float r4[4];
  float am = 0.f;
#pragma unroll
  for (int it = 0; it < 2; ++it) {
    const float4 v = *reinterpret_cast<const float4*>(x + (size_t)(it * 256 + tid) * 4);
    am = fmaxf(am, fmaxf(fmaxf(fabsf(v.x), fabsf(v.y)), fmaxf(fabsf(v.z), fabsf(v.w))));
  }
  const float bm = blockMax256(am, r4);
  if (tid == 0) atomicMax(vmax, __float_as_uint(bm));
}

// k fp32 -> mixed-quant int codes as bf16 + chosen scale per row
__global__ __launch_bounds__(256) void k_kint(const float* __restrict__ Kb,
                                              const float* __restrict__ s4,
                                              const float* __restrict__ smix,
                                              const int* __restrict__ sel,
                                              short* __restrict__ ki,
                                              float* __restrict__ skg) {
  const int row = blockIdx.x;
  const int tid = threadIdx.x;
  const int t = row & (kT - 1);
  const float s = sel[t] ? smix[t] : s4[row];
  const float* x = Kb + (size_t)row * kE;
#pragma unroll
  for (int it = 0; it < 2; ++it) {
    const int i = (it * 256 + tid) * 4;
    const float4 v = *reinterpret_cast<const float4*>(x + i);
    short4 q;
    q.x = (short)bfr(rintf(v.x / s));
    q.y = (short)bfr(rintf(v.y / s));
    q.z = (short)bfr(rintf(v.z / s));
    q.w = (short)bfr(rintf(v.w / s));
    *reinterpret_cast<short4*>(ki + (size_t)row * kE + i) = q;
  }
  if (tid == 0) skg[row] = s;
}

// v fp32 -> int codes as bf16, transposed per head: vt[(bh*64+d)*1024 + t]
__global__ __launch_bounds__(256) void k_vint(const float* __restrict__ Vb,
                                              const unsigned* __restrict__ vmax,
                                              short* __restrict__ vt) {
  const int tt = blockIdx.x;
  const int bh = blockIdx.y;
  const int b = bh >> 5, h = bh & 31;
  const float sv = fmaxf(__uint_as_float(*vmax), 1e-5f) / 7.f;
  __shared__ short tr[64][80];
  const int tid = threadIdx.x;
#pragma unroll
  for (int i = 0; i < 4; ++i) {
    const int e = i * 256 + tid;
    const int tok = e >> 4, d4 = (e & 15) * 4;
    const float4 v = *reinterpret_cast<const float4*>(
        &Vb[(size_t)(b * kT + tt * 64 + tok) * kE + h * 64 + d4]);
    tr[d4 + 0][tok] = (short)bfr(rintf(v.x / sv));
    tr[d4 + 1][tok] = (short)bfr(rintf(v.y / sv));
    tr[d4 + 2][tok] = (short)bfr(rintf(v.z / sv));
    tr[d4 + 3][tok] = (short)bfr(rintf(v.w / sv));
  }
  __syncthreads();
#pragma unroll
  for (int i = 0; i < 2; ++i) {
    const int e = i * 256 + tid;
    const int d = e >> 3, u = e & 7;
    const bf16x8 row = *reinterpret_cast<const bf16x8*>(&tr[d][u * 8]);
    *reinterpret_cast<bf16x8*>(&vt[(size_t)(bh * 64 + d) * kT + tt * 64 + u * 8]) = row;
  }
}

// ---------------- int8 MFMA GEMM: Y = (Ai8*sa) @ (Bi8*sw)^T + bias ----------------
__global__ __launch_bounds__(256) void k_gemm_i8(const int8_t* __restrict__ A,
                                                 const float* __restrict__ sa,
                                                 const int8_t* __restrict__ Bw,
                                                 const float* __restrict__ sw,
                                                 const float* __restrict__ bias,
                                                 float* __restrict__ Y) {
  __shared__ int8_t As[2][128 * 64];
  __shared__ int8_t Bs[2][128 * 64];
  const int tid = threadIdx.x;
  const int lane = tid & 63, w = tid >> 6;
  const int g = lane >> 4, c16 = lane & 15;
  const int m0 = blockIdx.y * 128, n0 = blockIdx.x * 128;
  const int wm = (w >> 1) * 64, wn = (w & 1) * 64;

  const i32x4 zero = {0, 0, 0, 0};
  i32x4 acc[4][4];
#pragma unroll
  for (int i = 0; i < 4; ++i)
#pragma unroll
    for (int j = 0; j < 4; ++j) acc[i][j] = zero;

  const int srow = tid >> 2, su = tid & 3;
  auto stage = [&](int buf, int k0) {
#pragma unroll
    for (int i = 0; i < 2; ++i) {
      const int row = i * 64 + srow;
      const int uoff = ((su ^ (row & 3)) << 4);  // pre-swizzled source -> swizzled LDS
      gload16(A + (size_t)(m0 + row) * kE + k0 + uoff, &As[buf][row * 64 + su * 16]);
      gload16(Bw + (size_t)(n0 + row) * kE + k0 + uoff, &Bs[buf][row * 64 + su * 16]);
    }
  };

  stage(0, 0);
  __syncthreads();
  int cur = 0;
  for (int k0 = 0; k0 < kE; k0 += 64) {
    if (k0 + 64 < kE) stage(cur ^ 1, k0 + 64);
    i32x4 av[4], bv[4];
#pragma unroll
    for (int f = 0; f < 4; ++f) {
      const int ar = wm + f * 16 + c16;
      av[f] = *reinterpret_cast<const i32x4*>(&As[cur][ar * 64 + ((g ^ (c16 & 3)) << 4)]);
      const int br = wn + f * 16 + c16;
      bv[f] = *reinterpret_cast<const i32x4*>(&Bs[cur][br * 64 + ((g ^ (c16 & 3)) << 4)]);
    }
#pragma unroll
    for (int fm = 0; fm < 4; ++fm)
#pragma unroll
      for (int fn = 0; fn < 4; ++fn) acc[fm][fn] = MFMA_I8(av[fm], bv[fn], acc[fm][fn]);
    __syncthreads();
    cur ^= 1;
  }

#pragma unroll
  for (int fn = 0; fn < 4; ++fn) {
    const int n = n0 + wn + fn * 16 + c16;
    const float swn = sw[n], bn = bias[n];
#pragma unroll
    for (int fm = 0; fm < 4; ++fm) {
#pragma unroll
      for (int r = 0; r < 4; ++r) {
        const int m = m0 + wm + fm * 16 + g * 4 + r;
        Y[(size_t)m * kE + n] = (float)acc[fm][fn][r] * sa[m] * swn + bn;
      }
    }
  }
}

// ---------------- attention pass 1 (MFMA, swapped S^T) ----------------
__global__ __launch_bounds__(256) void k_attn1(const short* __restrict__ qi,
                                               const short* __restrict__ khi,
                                               const short* __restrict__ klo,
                                               const float* __restrict__ sqg,
                                               float* __restrict__ accPart) {
  const int rt = blockIdx.x, bh = blockIdx.y;
  const int b = bh >> 5, h = bh & 31;
  const int tid = threadIdx.x, lane = tid & 63, w = tid >> 6;
  const int g = lane >> 4, c16 = lane & 15;
  const int swz = c16 & 7;
  const int wrow = w * 16 + c16;

  __shared__ short hbuf[2][64 * 64];
  __shared__ short lbuf[2][64 * 64];
  __shared__ float accp[4][1024];

  for (int i = tid; i < 4096; i += 256) ((float*)accp)[i] = 0.f;

  const int qtok = b * kT + rt * 64 + wrow;
  bf16x8 qf[2];
  qf[0] = *reinterpret_cast<const bf16x8*>(qi + (size_t)qtok * kE + h * 64 + g * 8);
  qf[1] = *reinterpret_cast<const bf16x8*>(qi + (size_t)qtok * kE + h * 64 + 32 + g * 8);
  const float sq = sqg[qtok];

  const int st8 = tid >> 3, su = tid & 7;
  auto stage = [&](int buf, int kt) {
    const int tokb = b * kT + kt * 64;
#pragma unroll
    for (int i = 0; i < 2; ++i) {
      const int tok = i * 32 + st8;
      const size_t gsrc = (size_t)(tokb + tok) * kE + h * 64 + ((su ^ (tok & 7)) << 3);
      gload16(khi + gsrc, &hbuf[buf][tok * 64 + su * 8]);
      gload16(klo + gsrc, &lbuf[buf][tok * 64 + su * 8]);
    }
  };

  float m = NEG_INF, l = 0.f;
  stage(0, 0);
  __syncthreads();
  int cur = 0;

  // ---- phase A: row stats ----
  for (int kt = 0; kt <= rt; ++kt) {
    if (kt < rt) stage(cur ^ 1, kt + 1);
    f32x4 sf[4];
#pragma unroll
    for (int f = 0; f < 4; ++f) {
      sf[f] = (f32x4){0.f, 0.f, 0.f, 0.f};
      const int tokl = f * 16 + c16;
      bf16x8 a;
      a = *reinterpret_cast<const bf16x8*>(&hbuf[cur][tokl * 64 + ((g ^ swz) << 3)]);
      sf[f] = MFMA_BF16(a, qf[0], sf[f]);
      a = *reinterpret_cast<const bf16x8*>(&hbuf[cur][tokl * 64 + (((4 + g) ^ swz) << 3)]);
      sf[f] = MFMA_BF16(a, qf[1], sf[f]);
      a = *reinterpret_cast<const bf16x8*>(&lbuf[cur][tokl * 64 + ((g ^ swz) << 3)]);
      sf[f] = MFMA_BF16(a, qf[0], sf[f]);
      a = *reinterpret_cast<const bf16x8*>(&lbuf[cur][tokl * 64 + (((4 + g) ^ swz) << 3)]);
      sf[f] = MFMA_BF16(a, qf[1], sf[f]);
    }
    float pm = NEG_INF;
    float p[4][4];
#pragma unroll
    for (int f = 0; f < 4; ++f)
#pragma unroll
      for (int r = 0; r < 4; ++r) {
        const int tokd = f * 16 + g * 4 + r;
        float s = sf[f][r] * sq;
        if (kt == rt && tokd > wrow) s = NEG_INF;
        p[f][r] = s;
        pm = fmaxf(pm, s);
      }
    pm = fmaxf(pm, __shfl_xor(pm, 16));
    pm = fmaxf(pm, __shfl_xor(pm, 32));
    const float mn = fmaxf(m, pm);
    const float fsc = expf(m - mn);
    float rs = 0.f;
#pragma unroll
    for (int f = 0; f < 4; ++f)
#pragma unroll
      for (int r = 0; r < 4; ++r) rs += expf(p[f][r] - mn);
    rs += __shfl_xor(rs, 16);
    rs += __shfl_xor(rs, 32);
    l = l * fsc + rs;
    m = mn;
    __syncthreads();
    cur ^= 1;
  }
  const float il = 1.f / l;

  // ---- phase B: normalized column sums ----
  stage(cur ^ 1, 0);
  __syncthreads();
  cur ^= 1;
  for (int kt = 0; kt <= rt; ++kt) {
    if (kt < rt) stage(cur ^ 1, kt + 1);
    f32x4 sf[4];
#pragma unroll
    for (int f = 0; f < 4; ++f) {
      sf[f] = (f32x4){0.f, 0.f, 0.f, 0.f};
      const int tokl = f * 16 + c16;
      bf16x8 a;
      a = *reinterpret_cast<const bf16x8*>(&hbuf[cur][tokl * 64 + ((g ^ swz) << 3)]);
      sf[f] = MFMA_BF16(a, qf[0], sf[f]);
      a = *reinterpret_cast<const bf16x8*>(&hbuf[cur][tokl * 64 + (((4 + g) ^ swz) << 3)]);
      sf[f] = MFMA_BF16(a, qf[1], sf[f]);
      a = *reinterpret_cast<const bf16x8*>(&lbuf[cur][tokl * 64 + ((g ^ swz) << 3)]);
      sf[f] = MFMA_BF16(a, qf[0], sf[f]);
      a = *reinterpret_cast<const bf16x8*>(&lbuf[cur][tokl * 64 + (((4 + g) ^ swz) << 3)]);
      sf[f] = MFMA_BF16(a, qf[1], sf[f]);
    }
#pragma unroll
    for (int f = 0; f < 4; ++f)
#pragma unroll
      for (int r = 0; r < 4; ++r) {
        const int tokd = f * 16 + g * 4 + r;
        float s = sf[f][r] * sq;
        if (kt == rt && tokd > wrow) s = NEG_INF;
        float v = expf(s - m) * il;
        v += __shfl_xor(v, 1);
        v += __shfl_xor(v, 2);
        v += __shfl_xor(v, 4);
        v += __shfl_xor(v, 8);
        if (c16 == 0) accp[w][kt * 64 + tokd] += v;
      }
    __syncthreads();
    cur ^= 1;
  }
  for (int i = tid; i < 1024; i += 256)
    accPart[(size_t)(bh * 16 + rt) * 1024 + i] =
        accp[0][i] + accp[1][i] + accp[2][i] + accp[3][i];
}

__global__ __launch_bounds__(256) void k_accreduce(const float* __restrict__ part,
                                                   float* __restrict__ acc) {
  const int j = blockIdx.x;
  const int tid = threadIdx.x;
  float s = 0.f;
  for (int p = tid; p < 1024; p += 256) s += part[(size_t)p * 1024 + j];
  __shared__ float r4[4];
  const float ws = waveReduceSum(s);
  if ((tid & 63) == 0) r4[tid >> 6] = ws;
  __syncthreads();
  if (tid == 0) {
    const float t = r4[0] + r4[1] + r4[2] + r4[3];
    acc[j] = t / (float)(kT - j) / 64.f;
  }
}

__global__ __launch_bounds__(256) void k_topk(const float* __restrict__ acc,
                                              int* __restrict__ sel) {
  const int gq = blockIdx.x;
  const int i = threadIdx.x;
  __shared__ float v[256];
  const float vi = acc[gq * 256 + i];
  v[i] = vi;
  __syncthreads();
  int rank = 0;
  for (int j = 0; j < 256; ++j) {
    const float vj = v[j];
    rank += (vj > vi) || (vj == vi && j < i);
  }
  sel[gq * 256 + i] = (rank < 128) ? 1 : 0;
}

// ---------------- attention pass 2 (MFMA flash, swapped) ----------------
__global__ __launch_bounds__(256) void k_attn2(const short* __restrict__ qi,
                                               const short* __restrict__ ki,
                                               const short* __restrict__ vt,
                                               const float* __restrict__ sqg,
                                               const float* __restrict__ skg,
                                               const unsigned* __restrict__ vmax,
                                               float* __restrict__ ctx) {
  const int rt = blockIdx.x, bh = blockIdx.y;
  const int b = bh >> 5, h = bh & 31;
  const int tid = threadIdx.x, lane = tid & 63, w = tid >> 6;
  const int g = lane >> 4, c16 = lane & 15;
  const int swz = c16 & 7;
  const int wrow = w * 16 + c16;

  __shared__ short kbuf[2][64 * 64];
  __shared__ short vbuf[2][64 * 64];
  __shared__ float skl[2][64];

  const int qtok = b * kT + rt * 64 + wrow;
  bf16x8 qf[2];
  qf[0] = *reinterpret_cast<const bf16x8*>(qi + (size_t)qtok * kE + h * 64 + g * 8);
  qf[1] = *reinterpret_cast<const bf16x8*>(qi + (size_t)qtok * kE + h * 64 + 32 + g * 8);
  const float sq = sqg[qtok];
  const float sv = fmaxf(__uint_as_float(*vmax), 1e-5f) / 7.f;

  const int st8 = tid >> 3, su = tid & 7;
  auto stage = [&](int buf, int kt) {
    const int tokb = b * kT + kt * 64;
#pragma unroll
    for (int i = 0; i < 2; ++i) {
      const int tok = i * 32 + st8;
      gload16(ki + (size_t)(tokb + tok) * kE + h * 64 + ((su ^ (tok & 7)) << 3),
              &kbuf[buf][tok * 64 + su * 8]);
      gload16(vt + (size_t)(bh * 64 + tok) * kT + kt * 64 + ((su ^ (tok & 7)) << 3),
              &vbuf[buf][tok * 64 + su * 8]);
    }
    if (tid < 64) skl[buf][tid] = skg[tokb + tid];
  };

  float m = NEG_INF, l = 0.f;
  f32x4 ot[4];
#pragma unroll
  for (int f = 0; f < 4; ++f) ot[f] = (f32x4){0.f, 0.f, 0.f, 0.f};

  stage(0, 0);
  __syncthreads();
  int cur = 0;

  const int srcLo = c16 | ((g & 1) << 5);
  const int srcHi = srcLo | 16;
  const bool selq = ((g >> 1) & 1) != 0;

  for (int kt = 0; kt <= rt; ++kt) {
    if (kt < rt) stage(cur ^ 1, kt + 1);
    // S^T = K_int @ Q_int^T  (integer-exact)
    f32x4 sf[4];
#pragma unroll
    for (int f = 0; f < 4; ++f) {
      sf[f] = (f32x4){0.f, 0.f, 0.f, 0.f};
      const int tokl = f * 16 + c16;
      bf16x8 a;
      a = *reinterpret_cast<const bf16x8*>(&kbuf[cur][tokl * 64 + ((g ^ swz) << 3)]);
      sf[f] = MFMA_BF16(a, qf[0], sf[f]);
      a = *reinterpret_cast<const bf16x8*>(&kbuf[cur][tokl * 64 + (((4 + g) ^ swz) << 3)]);
      sf[f] = MFMA_BF16(a, qf[1], sf[f]);
    }
    // scores + online softmax
    float p[4][4];
    float pm = NEG_INF;
#pragma unroll
    for (int f = 0; f < 4; ++f)
#pragma unroll
      for (int r = 0; r < 4; ++r) {
        const int tokd = f * 16 + g * 4 + r;
        float s = sf[f][r] * sq * skl[cur][tokd];
        if (kt == rt && tokd > wrow) s = NEG_INF;
        p[f][r] = s;
        pm = fmaxf(pm, s);
      }
    pm = fmaxf(pm, __shfl_xor(pm, 16));
    pm = fmaxf(pm, __shfl_xor(pm, 32));
    const float mn = fmaxf(m, pm);
    const float fsc = expf(m - mn);
    m = mn;
    float rs = 0.f;
#pragma unroll
    for (int f = 0; f < 4; ++f)
#pragma unroll
      for (int r = 0; r < 4; ++r) {
        const float e = expf(p[f][r] - mn);
        p[f][r] = e;
        rs += e;
      }
    rs += __shfl_xor(rs, 16);
    rs += __shfl_xor(rs, 32);
    l = l * fsc + rs;
#pragma unroll
    for (int f = 0; f < 4; ++f)
#pragma unroll
      for (int r = 0; r < 4; ++r) ot[f][r] *= fsc;

    // P (hi+lo bf16) redistribution -> B fragments, then PV
    float lof[4][4];
#pragma unroll
    for (int f = 0; f < 4; ++f)
#pragma unroll
      for (int r = 0; r < 4; ++r) {
        const unsigned hb = bfr(p[f][r]);
        lof[f][r] = p[f][r] - bf2f(hb);
      }
#pragma unroll
    for (int c = 0; c < 2; ++c) {
      const unsigned q0a = pk2(p[2 * c][0], p[2 * c][1]);
      const unsigned q0b = pk2(p[2 * c][2], p[2 * c][3]);
      const unsigned q1a = pk2(p[2 * c + 1][0], p[2 * c + 1][1]);
      const unsigned q1b = pk2(p[2 * c + 1][2], p[2 * c + 1][3]);
      const unsigned w0a = pk2(lof[2 * c][0], lof[2 * c][1]);
      const unsigned w0b = pk2(lof[2 * c][2], lof[2 * c][3]);
      const unsigned w1a = pk2(lof[2 * c + 1][0], lof[2 * c + 1][1]);
      const unsigned w1b = pk2(lof[2 * c + 1][2], lof[2 * c + 1][3]);
      unsigned a0, a1;
      union { unsigned u[4]; bf16x8 v; } Bh, Bl;
      a0 = __shfl(q0a, srcLo); a1 = __shfl(q1a, srcLo); Bh.u[0] = selq ? a1 : a0;
      a0 = __shfl(q0b, srcLo); a1 = __shfl(q1b, srcLo); Bh.u[1] = selq ? a1 : a0;
      a0 = __shfl(q0a, srcHi); a1 = __shfl(q1a, srcHi); Bh.u[2] = selq ? a1 : a0;
      a0 = __shfl(q0b, srcHi); a1 = __shfl(q1b, srcHi); Bh.u[3] = selq ? a1 : a0;
      a0 = __shfl(w0a, srcLo); a1 = __shfl(w1a, srcLo); Bl.u[0] = selq ? a1 : a0;
      a0 = __shfl(w0b, srcLo); a1 = __shfl(w1b, srcLo); Bl.u[1] = selq ? a1 : a0;
      a0 = __shfl(w0a, srcHi); a1 = __shfl(w1a, srcHi); Bl.u[2] = selq ? a1 : a0;
      a0 = __shfl(w0b, srcHi); a1 = __shfl(w1b, srcHi); Bl.u[3] = selq ? a1 : a0;
#pragma unroll
      for (int fd = 0; fd < 4; ++fd) {
        const int d = fd * 16 + c16;
        const bf16x8 va = *reinterpret_cast<const bf16x8*>(
            &vbuf[cur][d * 64 + ((((c << 2) | g) ^ swz) << 3)]);
        ot[fd] = MFMA_BF16(va, Bh.v, ot[fd]);
        ot[fd] = MFMA_BF16(va, Bl.v, ot[fd]);
      }
    }
    __syncthreads();
    cur ^= 1;
  }

  const float il = sv / l;
#pragma unroll
  for (int fd = 0; fd < 4; ++fd) {
    float4 o;
    o.x = ot[fd][0] * il;
    o.y = ot[fd][1] * il;
    o.z = ot[fd][2] * il;
    o.w = ot[fd][3] * il;
    *reinterpret_cast<float4*>(&ctx[(size_t)qtok * kE + h * 64 + fd * 16 + g * 4]) = o;
  }
}

// ---------------- launcher ----------------
extern "C" void kernel_launch(void* const* d_in, const int* in_sizes, int n_in,
                              void* d_out, int out_size, void* d_ws, size_t ws_size,
                              hipStream_t stream) {
  (void)in_sizes; (void)n_in; (void)out_size; (void)ws_size;
  const float* hs = (const float*)d_in[0];
  const float* Wq = (const float*)d_in[2];
  const float* bq = (const float*)d_in[3];
  const float* Wk = (const float*)d_in[4];
  const float* bk = (const float*)d_in[5];
  const float* Wv = (const float*)d_in[6];
  const float* bv = (const float*)d_in[7];
  const float* Wo = (const float*)d_in[8];
  const float* bo = (const float*)d_in[9];
  float* out = (float*)d_out;

  char* p = (char*)d_ws;
  auto take = [&](size_t bytes) {
    char* r = p;
    p += (bytes + 255) & ~(size_t)255;
    return r;
  };
  float* qb  = (float*)take((size_t)2048 * 2048 * 4);  // later khi+klo, later kint+vt
  float* kb  = (float*)take((size_t)2048 * 2048 * 4);
  float* vb  = (float*)take((size_t)2048 * 2048 * 4);
  float* ctx = (float*)take((size_t)2048 * 2048 * 4);  // accPart alias (first 4MB)
  short* qiB = (short*)take((size_t)2048 * 2048 * 2);
  int8_t* xq  = (int8_t*)take((size_t)2048 * 2048);
  int8_t* wbuf = (int8_t*)take((size_t)2048 * 2048);
  float* sX   = (float*)take(2048 * 4);
  float* sW   = (float*)take(2048 * 4);
  float* sC   = (float*)take(2048 * 4);
  float* s4v  = (float*)take(2048 * 4);
  float* smix = (float*)take(1024 * 4);
  float* accv = (float*)take(1024 * 4);
  int*   sel  = (int*)take(1024 * 4);
  float* sqg  = (float*)take(2048 * 4);
  float* skg  = (float*)take(2048 * 4);
  unsigned* vmax = (unsigned*)take(256);

  short* khi = (short*)qb;
  short* klo = (short*)qb + (size_t)2048 * 2048;
  short* kint = khi;          // reuses khi region after attn1
  short* vtp  = klo;          // reuses klo region after attn1
  float* accPart = ctx;       // consumed before attn2 writes ctx
  int8_t* cq = xq;

  dim3 gg(16, 16);
  dim3 ga(16, 64);

  k_rowquant_i8<<<2048, 256, 0, stream>>>(hs, xq, sX);
  k_rowquant_i8<<<2048, 256, 0, stream>>>(Wq, wbuf, sW);
  k_gemm_i8<<<gg, 256, 0, stream>>>(xq, sX, wbuf, sW, bq, qb);
  k_rowquant_i8<<<2048, 256, 0, stream>>>(Wk, wbuf, sW);
  k_gemm_i8<<<gg, 256, 0, stream>>>(xq, sX, wbuf, sW, bk, kb);
  k_rowquant_i8<<<2048, 256, 0, stream>>>(Wv, wbuf, sW);
  k_gemm_i8<<<gg, 256, 0, stream>>>(xq, sX, wbuf, sW, bv, vb);

  k_q2int<<<2048, 256, 0, stream>>>(qb, qiB, sqg);
  k_ksplit<<<2048, 256, 0, stream>>>(kb, khi, klo);

  k_attn1<<<ga, 256, 0, stream>>>(qiB, khi, klo, sqg, accPart);
  k_accreduce<<<1024, 256, 0, stream>>>(accPart, accv);
  k_topk<<<4, 256, 0, stream>>>(accv, sel);

  k_kscale<<<2048, 256, 0, stream>>>(kb, s4v, smix);
  k_init<<<1, 64, 0, stream>>>(vmax);
  k_vabsmax<<<2048, 256, 0, stream>>>(vb, vmax);
  k_kint<<<2048, 256, 0, stream>>>(kb, s4v, smix, sel, kint, skg);
  k_vint<<<ga, 256, 0, stream>>>(vb, vmax, vtp);

  k_attn2<<<ga, 256, 0, stream>>>(qiB, kint, vtp, sqg, skg, vmax, ctx);

  k_rowquant_i8<<<2048, 256, 0, stream>>>(ctx, cq, sC);
  k_rowquant_i8<<<2048, 256, 0, stream>>>(Wo, wbuf, sW);
  k_gemm_i8<<<gg, 256, 0, stream>>>(cq, sC, wbuf, sW, bo, out);
}

// Round 3
// 328.147 us; speedup vs baseline: 5.1779x; 1.3875x over previous
//
#include <hip/hip_runtime.h>
#include <stdint.h>

#define NEG_INF (-__builtin_inff())
#define L2E 1.4426950408889634f

namespace {
constexpr int kT   = 1024;
constexpr int kE   = 2048;
}

using bf16x8 = __attribute__((ext_vector_type(8))) short;
using f32x4  = __attribute__((ext_vector_type(4))) float;
using i32x4  = __attribute__((ext_vector_type(4))) int;

#define MFMA_BF16(a, b, c) __builtin_amdgcn_mfma_f32_16x16x32_bf16((a), (b), (c), 0, 0, 0)
#define MFMA_I8(a, b, c)   __builtin_amdgcn_mfma_i32_16x16x64_i8((a), (b), (c), 0, 0, 0)

// ---------------- small helpers ----------------
__device__ __forceinline__ void gload16(const void* g, void* l) {
  __builtin_amdgcn_global_load_lds((const __attribute__((address_space(1))) unsigned*)g,
                                   (__attribute__((address_space(3))) unsigned*)l, 16, 0, 0);
}
__device__ __forceinline__ unsigned bfr(float x) {  // f32 -> bf16 bits (RNE)
  unsigned u = __float_as_uint(x);
  return (u + 0x7FFFu + ((u >> 16) & 1u)) >> 16;
}
__device__ __forceinline__ float bf2f(unsigned h) { return __uint_as_float(h << 16); }
__device__ __forceinline__ unsigned pk2(float a, float b) { return bfr(a) | (bfr(b) << 16); }
__device__ __forceinline__ float fexp2(float x) { return __builtin_amdgcn_exp2f(x); }

__device__ __forceinline__ float waveReduceMax(float v) {
#pragma unroll
  for (int o = 32; o > 0; o >>= 1) v = fmaxf(v, __shfl_down(v, o, 64));
  return v;
}
__device__ __forceinline__ float waveReduceSum(float v) {
#pragma unroll
  for (int o = 32; o > 0; o >>= 1) v += __shfl_down(v, o, 64);
  return v;
}
__device__ __forceinline__ float blockMax256(float v, float* r4) {
  const int tid = threadIdx.x;
  float wm = waveReduceMax(v);
  if ((tid & 63) == 0) r4[tid >> 6] = wm;
  __syncthreads();
  float bm = fmaxf(fmaxf(r4[0], r4[1]), fmaxf(r4[2], r4[3]));
  __syncthreads();
  return bm;
}

// ---------------- quantization kernels ----------------
__global__ __launch_bounds__(256) void k_rowquant_i8(const float* __restrict__ X,
                                                     int8_t* __restrict__ Xq,
                                                     float* __restrict__ S) {
  const int row = blockIdx.x;
  const int tid = threadIdx.x;
  const float* x = X + (size_t)row * kE;
  __shared__ float r4[4];
  float am = 0.f;
#pragma unroll
  for (int it = 0; it < 2; ++it) {
    const float4 v = *reinterpret_cast<const float4*>(x + (size_t)(it * 256 + tid) * 4);
    am = fmaxf(am, fmaxf(fmaxf(fabsf(v.x), fabsf(v.y)), fmaxf(fabsf(v.z), fabsf(v.w))));
  }
  const float bm = blockMax256(am, r4);
  const float s = fmaxf(bm, 1e-5f) / 127.f;
  int8_t* xq = Xq + (size_t)row * kE;
#pragma unroll
  for (int it = 0; it < 2; ++it) {
    const int i = (it * 256 + tid) * 4;
    const float4 v = *reinterpret_cast<const float4*>(x + i);
    char4 q;
    q.x = (char)(int)rintf(v.x / s);
    q.y = (char)(int)rintf(v.y / s);
    q.z = (char)(int)rintf(v.z / s);
    q.w = (char)(int)rintf(v.w / s);
    *reinterpret_cast<char4*>(xq + i) = q;
  }
  if (tid == 0) S[row] = s;
}

// q fp32 -> int codes as bf16 (exact), sqg = s * D^-0.5
__global__ __launch_bounds__(256) void k_q2int(const float* __restrict__ Qb,
                                               short* __restrict__ qi,
                                               float* __restrict__ sqg) {
  const int row = blockIdx.x;
  const int tid = threadIdx.x;
  const float* x = Qb + (size_t)row * kE;
  __shared__ float r4[4];
  float am = 0.f;
  float4 v[2];
#pragma unroll
  for (int it = 0; it < 2; ++it) {
    v[it] = *reinterpret_cast<const float4*>(x + (size_t)(it * 256 + tid) * 4);
    am = fmaxf(am, fmaxf(fmaxf(fabsf(v[it].x), fabsf(v[it].y)), fmaxf(fabsf(v[it].z), fabsf(v[it].w))));
  }
  const float bm = blockMax256(am, r4);
  const float s = fmaxf(bm, 1e-5f) / 127.f;
#pragma unroll
  for (int it = 0; it < 2; ++it) {
    const int i = (it * 256 + tid) * 4;
    short4 q;
    q.x = (short)bfr(rintf(v[it].x / s));
    q.y = (short)bfr(rintf(v[it].y / s));
    q.z = (short)bfr(rintf(v[it].z / s));
    q.w = (short)bfr(rintf(v[it].w / s));
    *reinterpret_cast<short4*>(qi + (size_t)row * kE + i) = q;
  }
  if (tid == 0) sqg[row] = s * 0.125f;
}

// k fp32 -> hi/lo bf16 split
__global__ __launch_bounds__(256) void k_ksplit(const float* __restrict__ Kb,
                                                short* __restrict__ khi,
                                                short* __restrict__ klo) {
  const int row = blockIdx.x;
  const int tid = threadIdx.x;
  const float* x = Kb + (size_t)row * kE;
#pragma unroll
  for (int it = 0; it < 2; ++it) {
    const int i = (it * 256 + tid) * 4;
    const float4 v = *reinterpret_cast<const float4*>(x + i);
    short4 h, l;
    unsigned hb;
    hb = bfr(v.x); h.x = (short)hb; l.x = (short)bfr(v.x - bf2f(hb));
    hb = bfr(v.y); h.y = (short)hb; l.y = (short)bfr(v.y - bf2f(hb));
    hb = bfr(v.z); h.z = (short)hb; l.z = (short)bfr(v.z - bf2f(hb));
    hb = bfr(v.w); h.w = (short)hb; l.w = (short)bfr(v.w - bf2f(hb));
    *reinterpret_cast<short4*>(khi + (size_t)row * kE + i) = h;
    *reinterpret_cast<short4*>(klo + (size_t)row * kE + i) = l;
  }
}

__global__ __launch_bounds__(256) void k_kscale(const float* __restrict__ Kb,
                                                float* __restrict__ s4,
                                                float* __restrict__ smix) {
  const int row = blockIdx.x;
  const int tid = threadIdx.x;
  const float* x = Kb + (size_t)row * kE;
  __shared__ float r4[4];
  float am = 0.f;
#pragma unroll
  for (int it = 0; it < 2; ++it) {
    const float4 v = *reinterpret_cast<const float4*>(x + (size_t)(it * 256 + tid) * 4);
    am = fmaxf(am, fmaxf(fmaxf(fabsf(v.x), fabsf(v.y)), fmaxf(fabsf(v.z), fabsf(v.w))));
  }
  const float bm = blockMax256(am, r4);
  if (tid == 0) {
    s4[row] = fmaxf(bm, 1e-5f) / 7.f;
    if (row < kT) smix[row] = fmaxf(bm / 127.f, 1e-5f);
  }
}

__global__ void k_init(unsigned* vmax) {
  if (threadIdx.x == 0 && blockIdx.x == 0) *vmax = 0u;
}

__global__ __launch_bounds__(256) void k_vabsmax(const float* __restrict__ Vb,
                                                 unsigned* __restrict__ vmax) {
  const int row = blockIdx.x;
  const int tid = threadIdx.x;
  const float* x = Vb + (size_t)row * kE;
  __shared__ float r4[4];
  float am = 0.f;
#pragma unroll
  for (int it = 0; it < 2; ++it) {
    const float4 v = *reinterpret_cast<const float4*>(x + (size_t)(it * 256 + tid) * 4);
    am = fmaxf(am, fmaxf(fmaxf(fabsf(v.x), fabsf(v.y)), fmaxf(fabsf(v.z), fabsf(v.w))));
  }
  const float bm = blockMax256(am, r4);
  if (tid == 0) atomicMax(vmax, __float_as_uint(bm));
}

// k fp32 -> mixed-quant int codes as bf16 + chosen scale per row
__global__ __launch_bounds__(256) void k_kint(const float* __restrict__ Kb,
                                              const float* __restrict__ s4,
                                              const float* __restrict__ smix,
                                              const int* __restrict__ sel,
                                              short* __restrict__ ki,
                                              float* __restrict__ skg) {
  const int row = blockIdx.x;
  const int tid = threadIdx.x;
  const int t = row & (kT - 1);
  const float s = sel[t] ? smix[t] : s4[row];
  const float* x = Kb + (size_t)row * kE;
#pragma unroll
  for (int it = 0; it < 2; ++it) {
    const int i = (it * 256 + tid) * 4;
    const float4 v = *reinterpret_cast<const float4*>(x + i);
    short4 q;
    q.x = (short)bfr(rintf(v.x / s));
    q.y = (short)bfr(rintf(v.y / s));
    q.z = (short)bfr(rintf(v.z / s));
    q.w = (short)bfr(rintf(v.w / s));
    *reinterpret_cast<short4*>(ki + (size_t)row * kE + i) = q;
  }
  if (tid == 0) skg[row] = s;
}

// v fp32 -> int codes as bf16, transposed per head: vt[(bh*64+d)*1024 + t]
__global__ __launch_bounds__(256) void k_vint(const float* __restrict__ Vb,
                                              const unsigned* __restrict__ vmax,
                                              short* __restrict__ vt) {
  const int tt = blockIdx.x;
  const int bh = blockIdx.y;
  const int b = bh >> 5, h = bh & 31;
  const float sv = fmaxf(__uint_as_float(*vmax), 1e-5f) / 7.f;
  __shared__ short tr[64][80];
  const int tid = threadIdx.x;
#pragma unroll
  for (int i = 0; i < 4; ++i) {
    const int e = i * 256 + tid;
    const int tok = e >> 4, d4 = (e & 15) * 4;
    const float4 v = *reinterpret_cast<const float4*>(
        &Vb[(size_t)(b * kT + tt * 64 + tok) * kE + h * 64 + d4]);
    tr[d4 + 0][tok] = (short)bfr(rintf(v.x / sv));
    tr[d4 + 1][tok] = (short)bfr(rintf(v.y / sv));
    tr[d4 + 2][tok] = (short)bfr(rintf(v.z / sv));
    tr[d4 + 3][tok] = (short)bfr(rintf(v.w / sv));
  }
  __syncthreads();
#pragma unroll
  for (int i = 0; i < 2; ++i) {
    const int e = i * 256 + tid;
    const int d = e >> 3, u = e & 7;
    const bf16x8 row = *reinterpret_cast<const bf16x8*>(&tr[d][u * 8]);
    *reinterpret_cast<bf16x8*>(&vt[(size_t)(bh * 64 + d) * kT + tt * 64 + u * 8]) = row;
  }
}

// ---------------- int8 MFMA GEMM: Y = (Ai8*sa) @ (Bi8*sw)^T + bias ----------------
__global__ __launch_bounds__(256) void k_gemm_i8(const int8_t* __restrict__ A,
                                                 const float* __restrict__ sa,
                                                 const int8_t* __restrict__ Bw,
                                                 const float* __restrict__ sw,
                                                 const float* __restrict__ bias,
                                                 float* __restrict__ Y) {
  __shared__ int8_t As[2][128 * 64];
  __shared__ int8_t Bs[2][128 * 64];
  const int tid = threadIdx.x;
  const int lane = tid & 63, w = tid >> 6;
  const int g = lane >> 4, c16 = lane & 15;
  const int m0 = blockIdx.y * 128, n0 = blockIdx.x * 128;
  const int wm = (w >> 1) * 64, wn = (w & 1) * 64;

  const i32x4 zero = {0, 0, 0, 0};
  i32x4 acc[4][4];
#pragma unroll
  for (int i = 0; i < 4; ++i)
#pragma unroll
    for (int j = 0; j < 4; ++j) acc[i][j] = zero;

  const int srow = tid >> 2, su = tid & 3;
  auto stage = [&](int buf, int k0) {
#pragma unroll
    for (int i = 0; i < 2; ++i) {
      const int row = i * 64 + srow;
      const int uoff = ((su ^ (row & 3)) << 4);  // pre-swizzled source -> swizzled LDS
      gload16(A + (size_t)(m0 + row) * kE + k0 + uoff, &As[buf][row * 64 + su * 16]);
      gload16(Bw + (size_t)(n0 + row) * kE + k0 + uoff, &Bs[buf][row * 64 + su * 16]);
    }
  };

  stage(0, 0);
  __syncthreads();
  int cur = 0;
  for (int k0 = 0; k0 < kE; k0 += 64) {
    if (k0 + 64 < kE) stage(cur ^ 1, k0 + 64);
    i32x4 av[4], bv[4];
#pragma unroll
    for (int f = 0; f < 4; ++f) {
      const int ar = wm + f * 16 + c16;
      av[f] = *reinterpret_cast<const i32x4*>(&As[cur][ar * 64 + ((g ^ (c16 & 3)) << 4)]);
      const int br = wn + f * 16 + c16;
      bv[f] = *reinterpret_cast<const i32x4*>(&Bs[cur][br * 64 + ((g ^ (c16 & 3)) << 4)]);
    }
#pragma unroll
    for (int fm = 0; fm < 4; ++fm)
#pragma unroll
      for (int fn = 0; fn < 4; ++fn) acc[fm][fn] = MFMA_I8(av[fm], bv[fn], acc[fm][fn]);
    __syncthreads();
    cur ^= 1;
  }

#pragma unroll
  for (int fn = 0; fn < 4; ++fn) {
    const int n = n0 + wn + fn * 16 + c16;
    const float swn = sw[n], bn = bias[n];
#pragma unroll
    for (int fm = 0; fm < 4; ++fm) {
#pragma unroll
      for (int r = 0; r < 4; ++r) {
        const int m = m0 + wm + fm * 16 + g * 4 + r;
        Y[(size_t)m * kE + n] = (float)acc[fm][fn][r] * sa[m] * swn + bn;
      }
    }
  }
}

// ---------------- attention pass 1 ----------------
// Phase A (swapped S^T = K*Q): row stats.  Phase B (S = Q*K): column sums.
__global__ __launch_bounds__(256) void k_attn1(const short* __restrict__ qi,
                                               const short* __restrict__ khi,
                                               const short* __restrict__ klo,
                                               const float* __restrict__ sqg,
                                               float* __restrict__ accPart) {
  const int rt = blockIdx.x, bh = blockIdx.y;
  const int b = bh >> 5, h = bh & 31;
  const int tid = threadIdx.x, lane = tid & 63, w = tid >> 6;
  const int g = lane >> 4, c16 = lane & 15;
  const int swz = c16 & 7;

  __shared__ short qs[64 * 64];
  __shared__ short hbuf[2][64 * 64];
  __shared__ short lbuf[2][64 * 64];
  __shared__ float accL[1024];
  __shared__ float Arow[64], Crow[64];

  for (int i = tid; i < 1024; i += 256) accL[i] = 0.f;

  const int st8 = tid >> 3, su = tid & 7;
  // stage Q tile (same swizzle as K)
  {
    const int tokb = b * kT + rt * 64;
#pragma unroll
    for (int i = 0; i < 2; ++i) {
      const int tok = i * 32 + st8;
      gload16(qi + (size_t)(tokb + tok) * kE + h * 64 + ((su ^ (tok & 7)) << 3),
              &qs[tok * 64 + su * 8]);
    }
  }
  auto stage = [&](int buf, int kt) {
    const int tokb = b * kT + kt * 64;
#pragma unroll
    for (int i = 0; i < 2; ++i) {
      const int tok = i * 32 + st8;
      const size_t gsrc = (size_t)(tokb + tok) * kE + h * 64 + ((su ^ (tok & 7)) << 3);
      gload16(khi + gsrc, &hbuf[buf][tok * 64 + su * 8]);
      gload16(klo + gsrc, &lbuf[buf][tok * 64 + su * 8]);
    }
  };

  stage(0, 0);
  __syncthreads();

  // phase A per-warp Q fragment (rows w*16+c16), B-operand
  const int qrowA = w * 16 + c16;
  const bf16x8 qfA0 = *reinterpret_cast<const bf16x8*>(&qs[qrowA * 64 + ((g ^ swz) << 3)]);
  const bf16x8 qfA1 = *reinterpret_cast<const bf16x8*>(&qs[qrowA * 64 + (((4 + g) ^ swz) << 3)]);
  const float AyL = sqg[b * kT + rt * 64 + qrowA] * L2E;

  float m2 = NEG_INF, l = 0.f;
  int cur = 0;

  for (int kt = 0; kt <= rt; ++kt) {
    if (kt < rt) stage(cur ^ 1, kt + 1);
    float p2[4][4];
    float pm = NEG_INF;
#pragma unroll
    for (int f = 0; f < 4; ++f) {
      f32x4 sf = {0.f, 0.f, 0.f, 0.f};
      const int tokl = f * 16 + c16;
      bf16x8 a;
      a = *reinterpret_cast<const bf16x8*>(&hbuf[cur][tokl * 64 + ((g ^ swz) << 3)]);
      sf = MFMA_BF16(a, qfA0, sf);
      a = *reinterpret_cast<const bf16x8*>(&hbuf[cur][tokl * 64 + (((4 + g) ^ swz) << 3)]);
      sf = MFMA_BF16(a, qfA1, sf);
      a = *reinterpret_cast<const bf16x8*>(&lbuf[cur][tokl * 64 + ((g ^ swz) << 3)]);
      sf = MFMA_BF16(a, qfA0, sf);
      a = *reinterpret_cast<const bf16x8*>(&lbuf[cur][tokl * 64 + (((4 + g) ^ swz) << 3)]);
      sf = MFMA_BF16(a, qfA1, sf);
#pragma unroll
      for (int r = 0; r < 4; ++r) {
        float s2 = sf[r] * AyL;
        if (kt == rt && (f * 16 + g * 4 + r) > qrowA) s2 = NEG_INF;
        p2[f][r] = s2;
        pm = fmaxf(pm, s2);
      }
    }
    pm = fmaxf(pm, __shfl_xor(pm, 16));
    pm = fmaxf(pm, __shfl_xor(pm, 32));
    const bool upd = pm > m2 + 8.f;
    const float mn = upd ? fmaxf(m2, pm) : m2;
    const float fsc = fexp2(m2 - mn);
    float rs = 0.f;
#pragma unroll
    for (int f = 0; f < 4; ++f)
#pragma unroll
      for (int r = 0; r < 4; ++r) rs += fexp2(p2[f][r] - mn);
    rs += __shfl_xor(rs, 16);
    rs += __shfl_xor(rs, 32);
    l = l * fsc + rs;
    m2 = mn;
    __syncthreads();
    cur ^= 1;
  }

  if (g == 0) {
    Arow[qrowA] = AyL;
    Crow[qrowA] = -(m2 + __builtin_amdgcn_logf(l));
  }
  stage(0, 0);
  __syncthreads();

  // phase B constants + Q A-frags (hoisted; constant over kt)
  float Arr[4][4], Crr[4][4];
  bf16x8 qa0[4], qa1[4];
#pragma unroll
  for (int f = 0; f < 4; ++f) {
    const int qr = f * 16 + c16;
    qa0[f] = *reinterpret_cast<const bf16x8*>(&qs[qr * 64 + ((g ^ swz) << 3)]);
    qa1[f] = *reinterpret_cast<const bf16x8*>(&qs[qr * 64 + (((4 + g) ^ swz) << 3)]);
#pragma unroll
    for (int r = 0; r < 4; ++r) {
      Arr[f][r] = Arow[f * 16 + g * 4 + r];
      Crr[f][r] = Crow[f * 16 + g * 4 + r];
    }
  }

  const int ktokL = w * 16 + c16;  // this warp's column within tile
  cur = 0;
  for (int kt = 0; kt <= rt; ++kt) {
    if (kt < rt) stage(cur ^ 1, kt + 1);
    const bf16x8 kh0 = *reinterpret_cast<const bf16x8*>(&hbuf[cur][ktokL * 64 + ((g ^ swz) << 3)]);
    const bf16x8 kh1 = *reinterpret_cast<const bf16x8*>(&hbuf[cur][ktokL * 64 + (((4 + g) ^ swz) << 3)]);
    const bf16x8 kl0 = *reinterpret_cast<const bf16x8*>(&lbuf[cur][ktokL * 64 + ((g ^ swz) << 3)]);
    const bf16x8 kl1 = *reinterpret_cast<const bf16x8*>(&lbuf[cur][ktokL * 64 + (((4 + g) ^ swz) << 3)]);
    float csum = 0.f;
    if (kt < rt) {
#pragma unroll
      for (int f = 0; f < 4; ++f) {
        f32x4 sf = {0.f, 0.f, 0.f, 0.f};
        sf = MFMA_BF16(qa0[f], kh0, sf);
        sf = MFMA_BF16(qa1[f], kh1, sf);
        sf = MFMA_BF16(qa0[f], kl0, sf);
        sf = MFMA_BF16(qa1[f], kl1, sf);
#pragma unroll
        for (int r = 0; r < 4; ++r)
          csum += fexp2(fmaf(sf[r], Arr[f][r], Crr[f][r]));
      }
    } else {
#pragma unroll
      for (int f = 0; f < 4; ++f) {
        f32x4 sf = {0.f, 0.f, 0.f, 0.f};
        sf = MFMA_BF16(qa0[f], kh0, sf);
        sf = MFMA_BF16(qa1[f], kh1, sf);
        sf = MFMA_BF16(qa0[f], kl0, sf);
        sf = MFMA_BF16(qa1[f], kl1, sf);
#pragma unroll
        for (int r = 0; r < 4; ++r) {
          const float v = fexp2(fmaf(sf[r], Arr[f][r], Crr[f][r]));
          if (ktokL <= (f * 16 + g * 4 + r)) csum += v;  // causal mask on diagonal tile
        }
      }
    }
    csum += __shfl_xor(csum, 16);
    csum += __shfl_xor(csum, 32);
    if (g == 0) accL[kt * 64 + ktokL] += csum;
    __syncthreads();
    cur ^= 1;
  }

  for (int i = tid; i < 1024; i += 256)
    accPart[(size_t)(bh * 16 + rt) * 1024 + i] = accL[i];
}

__global__ __launch_bounds__(256) void k_accreduce(const float* __restrict__ part,
                                                   float* __restrict__ acc) {
  const int j = blockIdx.x;
  const int tid = threadIdx.x;
  float s = 0.f;
  for (int p = tid; p < 1024; p += 256) s += part[(size_t)p * 1024 + j];
  __shared__ float r4[4];
  const float ws = waveReduceSum(s);
  if ((tid & 63) == 0) r4[tid >> 6] = ws;
  __syncthreads();
  if (tid == 0) {
    const float t = r4[0] + r4[1] + r4[2] + r4[3];
    acc[j] = t / (float)(kT - j) / 64.f;
  }
}

__global__ __launch_bounds__(256) void k_topk(const float* __restrict__ acc,
                                              int* __restrict__ sel) {
  const int gq = blockIdx.x;
  const int i = threadIdx.x;
  __shared__ float v[256];
  const float vi = acc[gq * 256 + i];
  v[i] = vi;
  __syncthreads();
  int rank = 0;
  for (int j = 0; j < 256; ++j) {
    const float vj = v[j];
    rank += (vj > vi) || (vj == vi && j < i);
  }
  sel[gq * 256 + i] = (rank < 128) ? 1 : 0;
}

// ---------------- attention pass 2 (MFMA flash, swapped) ----------------
__global__ __launch_bounds__(256) void k_attn2(const short* __restrict__ qi,
                                               const short* __restrict__ ki,
                                               const short* __restrict__ vt,
                                               const float* __restrict__ sqg,
                                               const float* __restrict__ skg,
                                               const unsigned* __restrict__ vmax,
                                               float* __restrict__ ctx) {
  const int rt = blockIdx.x, bh = blockIdx.y;
  const int b = bh >> 5, h = bh & 31;
  const int tid = threadIdx.x, lane = tid & 63, w = tid >> 6;
  const int g = lane >> 4, c16 = lane & 15;
  const int swz = c16 & 7;
  const int wrow = w * 16 + c16;

  __shared__ short kbuf[2][64 * 64];
  __shared__ short vbuf[2][64 * 64];
  __shared__ float skl[2][64];

  const int qtok = b * kT + rt * 64 + wrow;
  bf16x8 qf[2];
  qf[0] = *reinterpret_cast<const bf16x8*>(qi + (size_t)qtok * kE + h * 64 + g * 8);
  qf[1] = *reinterpret_cast<const bf16x8*>(qi + (size_t)qtok * kE + h * 64 + 32 + g * 8);
  const float sq2 = sqg[qtok] * L2E;
  const float sv = fmaxf(__uint_as_float(*vmax), 1e-5f) / 7.f;

  const int st8 = tid >> 3, su = tid & 7;
  auto stage = [&](int buf, int kt) {
    const int tokb = b * kT + kt * 64;
#pragma unroll
    for (int i = 0; i < 2; ++i) {
      const int tok = i * 32 + st8;
      gload16(ki + (size_t)(tokb + tok) * kE + h * 64 + ((su ^ (tok & 7)) << 3),
              &kbuf[buf][tok * 64 + su * 8]);
      gload16(vt + (size_t)(bh * 64 + tok) * kT + kt * 64 + ((su ^ (tok & 7)) << 3),
              &vbuf[buf][tok * 64 + su * 8]);
    }
    if (tid < 64) skl[buf][tid] = skg[tokb + tid];
  };

  float m2 = NEG_INF, l = 0.f;
  f32x4 ot[4];
#pragma unroll
  for (int f = 0; f < 4; ++f) ot[f] = (f32x4){0.f, 0.f, 0.f, 0.f};

  stage(0, 0);
  __syncthreads();
  int cur = 0;

  const int srcLo = c16 | ((g & 1) << 5);
  const int srcHi = srcLo | 16;
  const bool selq = ((g >> 1) & 1) != 0;

  for (int kt = 0; kt <= rt; ++kt) {
    if (kt < rt) stage(cur ^ 1, kt + 1);
    // S^T = K_int @ Q_int^T  (integer-exact)
    f32x4 sf[4];
#pragma unroll
    for (int f = 0; f < 4; ++f) {
      sf[f] = (f32x4){0.f, 0.f, 0.f, 0.f};
      const int tokl = f * 16 + c16;
      bf16x8 a;
      a = *reinterpret_cast<const bf16x8*>(&kbuf[cur][tokl * 64 + ((g ^ swz) << 3)]);
      sf[f] = MFMA_BF16(a, qf[0], sf[f]);
      a = *reinterpret_cast<const bf16x8*>(&kbuf[cur][tokl * 64 + (((4 + g) ^ swz) << 3)]);
      sf[f] = MFMA_BF16(a, qf[1], sf[f]);
    }
    // scores (base-2 domain) + online softmax with defer-max
    float p[4][4];
    float pm = NEG_INF;
#pragma unroll
    for (int f = 0; f < 4; ++f)
#pragma unroll
      for (int r = 0; r < 4; ++r) {
        const int tokd = f * 16 + g * 4 + r;
        float s2 = sf[f][r] * skl[cur][tokd] * sq2;
        if (kt == rt && tokd > wrow) s2 = NEG_INF;
        p[f][r] = s2;
        pm = fmaxf(pm, s2);
      }
    pm = fmaxf(pm, __shfl_xor(pm, 16));
    pm = fmaxf(pm, __shfl_xor(pm, 32));
    const bool upd = pm > m2 + 8.f;
    const float mn = upd ? fmaxf(m2, pm) : m2;
    const float fsc = fexp2(m2 - mn);
    m2 = mn;
    float rs = 0.f;
#pragma unroll
    for (int f = 0; f < 4; ++f)
#pragma unroll
      for (int r = 0; r < 4; ++r) {
        const float e = fexp2(p[f][r] - mn);
        p[f][r] = e;
        rs += e;
      }
    rs += __shfl_xor(rs, 16);
    rs += __shfl_xor(rs, 32);
    l = l * fsc + rs;
    if (__any(upd)) {
#pragma unroll
      for (int f = 0; f < 4; ++f)
#pragma unroll
        for (int r = 0; r < 4; ++r) ot[f][r] *= fsc;
    }

    // P (hi+lo bf16) redistribution -> B fragments, then PV
    float lof[4][4];
#pragma unroll
    for (int f = 0; f < 4; ++f)
#pragma unroll
      for (int r = 0; r < 4; ++r) {
        const unsigned hb = bfr(p[f][r]);
        lof[f][r] = p[f][r] - bf2f(hb);
      }
#pragma unroll
    for (int c = 0; c < 2; ++c) {
      const unsigned q0a = pk2(p[2 * c][0], p[2 * c][1]);
      const unsigned q0b = pk2(p[2 * c][2], p[2 * c][3]);
      const unsigned q1a = pk2(p[2 * c + 1][0], p[2 * c + 1][1]);
      const unsigned q1b = pk2(p[2 * c + 1][2], p[2 * c + 1][3]);
      const unsigned w0a = pk2(lof[2 * c][0], lof[2 * c][1]);
      const unsigned w0b = pk2(lof[2 * c][2], lof[2 * c][3]);
      const unsigned w1a = pk2(lof[2 * c + 1][0], lof[2 * c + 1][1]);
      const unsigned w1b = pk2(lof[2 * c + 1][2], lof[2 * c + 1][3]);
      unsigned a0, a1;
      union { unsigned u[4]; bf16x8 v; } Bh, Bl;
      a0 = __shfl(q0a, srcLo); a1 = __shfl(q1a, srcLo); Bh.u[0] = selq ? a1 : a0;
      a0 = __shfl(q0b, srcLo); a1 = __shfl(q1b, srcLo); Bh.u[1] = selq ? a1 : a0;
      a0 = __shfl(q0a, srcHi); a1 = __shfl(q1a, srcHi); Bh.u[2] = selq ? a1 : a0;
      a0 = __shfl(q0b, srcHi); a1 = __shfl(q1b, srcHi); Bh.u[3] = selq ? a1 : a0;
      a0 = __shfl(w0a, srcLo); a1 = __shfl(w1a, srcLo); Bl.u[0] = selq ? a1 : a0;
      a0 = __shfl(w0b, srcLo); a1 = __shfl(w1b, srcLo); Bl.u[1] = selq ? a1 : a0;
      a0 = __shfl(w0a, srcHi); a1 = __shfl(w1a, srcHi); Bl.u[2] = selq ? a1 : a0;
      a0 = __shfl(w0b, srcHi); a1 = __shfl(w1b, srcHi); Bl.u[3] = selq ? a1 : a0;
#pragma unroll
      for (int fd = 0; fd < 4; ++fd) {
        const int d = fd * 16 + c16;
        const bf16x8 va = *reinterpret_cast<const bf16x8*>(
            &vbuf[cur][d * 64 + ((((c << 2) | g) ^ swz) << 3)]);
        ot[fd] = MFMA_BF16(va, Bh.v, ot[fd]);
        ot[fd] = MFMA_BF16(va, Bl.v, ot[fd]);
      }
    }
    __syncthreads();
    cur ^= 1;
  }

  const float il = sv / l;
#pragma unroll
  for (int fd = 0; fd < 4; ++fd) {
    float4 o;
    o.x = ot[fd][0] * il;
    o.y = ot[fd][1] * il;
    o.z = ot[fd][2] * il;
    o.w = ot[fd][3] * il;
    *reinterpret_cast<float4*>(&ctx[(size_t)qtok * kE + h * 64 + fd * 16 + g * 4]) = o;
  }
}

// ---------------- launcher ----------------
extern "C" void kernel_launch(void* const* d_in, const int* in_sizes, int n_in,
                              void* d_out, int out_size, void* d_ws, size_t ws_size,
                              hipStream_t stream) {
  (void)in_sizes; (void)n_in; (void)out_size; (void)ws_size;
  const float* hs = (const float*)d_in[0];
  const float* Wq = (const float*)d_in[2];
  const float* bq = (const float*)d_in[3];
  const float* Wk = (const float*)d_in[4];
  const float* bk = (const float*)d_in[5];
  const float* Wv = (const float*)d_in[6];
  const float* bv = (const float*)d_in[7];
  const float* Wo = (const float*)d_in[8];
  const float* bo = (const float*)d_in[9];
  float* out = (float*)d_out;

  char* p = (char*)d_ws;
  auto take = [&](size_t bytes) {
    char* r = p;
    p += (bytes + 255) & ~(size_t)255;
    return r;
  };
  float* qb  = (float*)take((size_t)2048 * 2048 * 4);  // later khi+klo, later kint+vt
  float* kb  = (float*)take((size_t)2048 * 2048 * 4);
  float* vb  = (float*)take((size_t)2048 * 2048 * 4);
  float* ctx = (float*)take((size_t)2048 * 2048 * 4);  // accPart alias (first 4MB)
  short* qiB = (short*)take((size_t)2048 * 2048 * 2);
  int8_t* xq  = (int8_t*)take((size_t)2048 * 2048);
  int8_t* wbuf = (int8_t*)take((size_t)2048 * 2048);
  float* sX   = (float*)take(2048 * 4);
  float* sW   = (float*)take(2048 * 4);
  float* sC   = (float*)take(2048 * 4);
  float* s4v  = (float*)take(2048 * 4);
  float* smix = (float*)take(1024 * 4);
  float* accv = (float*)take(1024 * 4);
  int*   sel  = (int*)take(1024 * 4);
  float* sqg  = (float*)take(2048 * 4);
  float* skg  = (float*)take(2048 * 4);
  unsigned* vmax = (unsigned*)take(256);

  short* khi = (short*)qb;
  short* klo = (short*)qb + (size_t)2048 * 2048;
  short* kint = khi;          // reuses khi region after attn1
  short* vtp  = klo;          // reuses klo region after attn1
  float* accPart = ctx;       // consumed before attn2 writes ctx
  int8_t* cq = xq;

  dim3 gg(16, 16);
  dim3 ga(16, 64);

  k_rowquant_i8<<<2048, 256, 0, stream>>>(hs, xq, sX);
  k_rowquant_i8<<<2048, 256, 0, stream>>>(Wq, wbuf, sW);
  k_gemm_i8<<<gg, 256, 0, stream>>>(xq, sX, wbuf, sW, bq, qb);
  k_rowquant_i8<<<2048, 256, 0, stream>>>(Wk, wbuf, sW);
  k_gemm_i8<<<gg, 256, 0, stream>>>(xq, sX, wbuf, sW, bk, kb);
  k_rowquant_i8<<<2048, 256, 0, stream>>>(Wv, wbuf, sW);
  k_gemm_i8<<<gg, 256, 0, stream>>>(xq, sX, wbuf, sW, bv, vb);

  k_q2int<<<2048, 256, 0, stream>>>(qb, qiB, sqg);
  k_ksplit<<<2048, 256, 0, stream>>>(kb, khi, klo);

  k_attn1<<<ga, 256, 0, stream>>>(qiB, khi, klo, sqg, accPart);
  k_accreduce<<<1024, 256, 0, stream>>>(accPart, accv);
  k_topk<<<4, 256, 0, stream>>>(accv, sel);

  k_kscale<<<2048, 256, 0, stream>>>(kb, s4v, smix);
  k_init<<<1, 64, 0, stream>>>(vmax);
  k_vabsmax<<<2048, 256, 0, stream>>>(vb, vmax);
  k_kint<<<2048, 256, 0, stream>>>(kb, s4v, smix, sel, kint, skg);
  k_vint<<<ga, 256, 0, stream>>>(vb, vmax, vtp);

  k_attn2<<<ga, 256, 0, stream>>>(qiB, kint, vtp, sqg, skg, vmax, ctx);

  k_rowquant_i8<<<2048, 256, 0, stream>>>(ctx, cq, sC);
  k_rowquant_i8<<<2048, 256, 0, stream>>>(Wo, wbuf, sW);
  k_gemm_i8<<<gg, 256, 0, stream>>>(cq, sC, wbuf, sW, bo, out);
}

// Round 4
// 254.704 us; speedup vs baseline: 6.6709x; 1.2883x over previous
//
#include <hip/hip_runtime.h>
#include <stdint.h>

#define NEG_INF (-__builtin_inff())
#define L2E 1.4426950408889634f

namespace {
constexpr int kT   = 1024;
constexpr int kE   = 2048;
}

using bf16x8 = __attribute__((ext_vector_type(8))) short;
using f32x4  = __attribute__((ext_vector_type(4))) float;
using i32x4  = __attribute__((ext_vector_type(4))) int;

#define MFMA_BF16(a, b, c) __builtin_amdgcn_mfma_f32_16x16x32_bf16((a), (b), (c), 0, 0, 0)
#define MFMA_I8(a, b, c)   __builtin_amdgcn_mfma_i32_16x16x64_i8((a), (b), (c), 0, 0, 0)

// ---------------- small helpers ----------------
__device__ __forceinline__ void gload16(const void* g, void* l) {
  __builtin_amdgcn_global_load_lds((const __attribute__((address_space(1))) unsigned*)g,
                                   (__attribute__((address_space(3))) unsigned*)l, 16, 0, 0);
}
__device__ __forceinline__ unsigned bfr(float x) {  // f32 -> bf16 bits (RNE)
  unsigned u = __float_as_uint(x);
  return (u + 0x7FFFu + ((u >> 16) & 1u)) >> 16;
}
__device__ __forceinline__ float bf2f(unsigned h) { return __uint_as_float(h << 16); }
__device__ __forceinline__ unsigned pk2(float a, float b) { return bfr(a) | (bfr(b) << 16); }
__device__ __forceinline__ float fexp2(float x) { return __builtin_amdgcn_exp2f(x); }

__device__ __forceinline__ float waveReduceMax(float v) {
#pragma unroll
  for (int o = 32; o > 0; o >>= 1) v = fmaxf(v, __shfl_down(v, o, 64));
  return v;
}
__device__ __forceinline__ float waveReduceSum(float v) {
#pragma unroll
  for (int o = 32; o > 0; o >>= 1) v += __shfl_down(v, o, 64);
  return v;
}
__device__ __forceinline__ float blockMax256(float v, float* r4) {
  const int tid = threadIdx.x;
  float wm = waveReduceMax(v);
  if ((tid & 63) == 0) r4[tid >> 6] = wm;
  __syncthreads();
  float bm = fmaxf(fmaxf(r4[0], r4[1]), fmaxf(r4[2], r4[3]));
  __syncthreads();
  return bm;
}

// ---------------- quantization kernels ----------------
__global__ __launch_bounds__(256) void k_rowquant_i8(const float* __restrict__ X,
                                                     int8_t* __restrict__ Xq,
                                                     float* __restrict__ S) {
  const int row = blockIdx.x;
  const int tid = threadIdx.x;
  const float* x = X + (size_t)row * kE;
  __shared__ float r4[4];
  float am = 0.f;
#pragma unroll
  for (int it = 0; it < 2; ++it) {
    const float4 v = *reinterpret_cast<const float4*>(x + (size_t)(it * 256 + tid) * 4);
    am = fmaxf(am, fmaxf(fmaxf(fabsf(v.x), fabsf(v.y)), fmaxf(fabsf(v.z), fabsf(v.w))));
  }
  const float bm = blockMax256(am, r4);
  const float s = fmaxf(bm, 1e-5f) / 127.f;
  int8_t* xq = Xq + (size_t)row * kE;
#pragma unroll
  for (int it = 0; it < 2; ++it) {
    const int i = (it * 256 + tid) * 4;
    const float4 v = *reinterpret_cast<const float4*>(x + i);
    char4 q;
    q.x = (char)(int)rintf(v.x / s);
    q.y = (char)(int)rintf(v.y / s);
    q.z = (char)(int)rintf(v.z / s);
    q.w = (char)(int)rintf(v.w / s);
    *reinterpret_cast<char4*>(xq + i) = q;
  }
  if (tid == 0) S[row] = s;
}

// all four weight matrices in one launch; blockIdx.y selects
__global__ __launch_bounds__(256) void k_rowquant_w4(const float* __restrict__ W0,
                                                     const float* __restrict__ W1,
                                                     const float* __restrict__ W2,
                                                     const float* __restrict__ W3,
                                                     int8_t* __restrict__ Q0,
                                                     int8_t* __restrict__ Q1,
                                                     int8_t* __restrict__ Q2,
                                                     int8_t* __restrict__ Q3,
                                                     float* __restrict__ S) {
  const int y = blockIdx.y;
  const float* W = (y == 0) ? W0 : (y == 1) ? W1 : (y == 2) ? W2 : W3;
  int8_t* Qp = (y == 0) ? Q0 : (y == 1) ? Q1 : (y == 2) ? Q2 : Q3;
  const int row = blockIdx.x;
  const int tid = threadIdx.x;
  const float* x = W + (size_t)row * kE;
  __shared__ float r4[4];
  float am = 0.f;
#pragma unroll
  for (int it = 0; it < 2; ++it) {
    const float4 v = *reinterpret_cast<const float4*>(x + (size_t)(it * 256 + tid) * 4);
    am = fmaxf(am, fmaxf(fmaxf(fabsf(v.x), fabsf(v.y)), fmaxf(fabsf(v.z), fabsf(v.w))));
  }
  const float bm = blockMax256(am, r4);
  const float s = fmaxf(bm, 1e-5f) / 127.f;
  int8_t* xq = Qp + (size_t)row * kE;
#pragma unroll
  for (int it = 0; it < 2; ++it) {
    const int i = (it * 256 + tid) * 4;
    const float4 v = *reinterpret_cast<const float4*>(x + i);
    char4 q;
    q.x = (char)(int)rintf(v.x / s);
    q.y = (char)(int)rintf(v.y / s);
    q.z = (char)(int)rintf(v.z / s);
    q.w = (char)(int)rintf(v.w / s);
    *reinterpret_cast<char4*>(xq + i) = q;
  }
  if (tid == 0) S[y * kE + row] = s;
}

// q fp32 -> int codes as bf16 (exact), sqg = s * D^-0.5
__global__ __launch_bounds__(256) void k_q2int(const float* __restrict__ Qb,
                                               short* __restrict__ qi,
                                               float* __restrict__ sqg) {
  const int row = blockIdx.x;
  const int tid = threadIdx.x;
  const float* x = Qb + (size_t)row * kE;
  __shared__ float r4[4];
  float am = 0.f;
  float4 v[2];
#pragma unroll
  for (int it = 0; it < 2; ++it) {
    v[it] = *reinterpret_cast<const float4*>(x + (size_t)(it * 256 + tid) * 4);
    am = fmaxf(am, fmaxf(fmaxf(fabsf(v[it].x), fabsf(v[it].y)), fmaxf(fabsf(v[it].z), fabsf(v[it].w))));
  }
  const float bm = blockMax256(am, r4);
  const float s = fmaxf(bm, 1e-5f) / 127.f;
#pragma unroll
  for (int it = 0; it < 2; ++it) {
    const int i = (it * 256 + tid) * 4;
    short4 q;
    q.x = (short)bfr(rintf(v[it].x / s));
    q.y = (short)bfr(rintf(v[it].y / s));
    q.z = (short)bfr(rintf(v[it].z / s));
    q.w = (short)bfr(rintf(v[it].w / s));
    *reinterpret_cast<short4*>(qi + (size_t)row * kE + i) = q;
  }
  if (tid == 0) sqg[row] = s * 0.125f;
}

// fused: k fp32 -> hi/lo bf16 split + scales (s4, smix)
__global__ __launch_bounds__(256) void k_ksplitscale(const float* __restrict__ Kb,
                                                     short* __restrict__ khi,
                                                     short* __restrict__ klo,
                                                     float* __restrict__ s4,
                                                     float* __restrict__ smix) {
  const int row = blockIdx.x;
  const int tid = threadIdx.x;
  const float* x = Kb + (size_t)row * kE;
  __shared__ float r4[4];
  float am = 0.f;
  float4 v[2];
#pragma unroll
  for (int it = 0; it < 2; ++it) {
    v[it] = *reinterpret_cast<const float4*>(x + (size_t)(it * 256 + tid) * 4);
    am = fmaxf(am, fmaxf(fmaxf(fabsf(v[it].x), fabsf(v[it].y)), fmaxf(fabsf(v[it].z), fabsf(v[it].w))));
  }
  const float bm = blockMax256(am, r4);
#pragma unroll
  for (int it = 0; it < 2; ++it) {
    const int i = (it * 256 + tid) * 4;
    short4 hh, ll;
    unsigned hb;
    hb = bfr(v[it].x); hh.x = (short)hb; ll.x = (short)bfr(v[it].x - bf2f(hb));
    hb = bfr(v[it].y); hh.y = (short)hb; ll.y = (short)bfr(v[it].y - bf2f(hb));
    hb = bfr(v[it].z); hh.z = (short)hb; ll.z = (short)bfr(v[it].z - bf2f(hb));
    hb = bfr(v[it].w); hh.w = (short)hb; ll.w = (short)bfr(v[it].w - bf2f(hb));
    *reinterpret_cast<short4*>(khi + (size_t)row * kE + i) = hh;
    *reinterpret_cast<short4*>(klo + (size_t)row * kE + i) = ll;
  }
  if (tid == 0) {
    s4[row] = fmaxf(bm, 1e-5f) / 7.f;
    if (row < kT) smix[row] = fmaxf(bm / 127.f, 1e-5f);
  }
}

__global__ void k_init(unsigned* vmax) {
  if (threadIdx.x == 0 && blockIdx.x == 0) *vmax = 0u;
}

__global__ __launch_bounds__(256) void k_vabsmax(const float* __restrict__ Vb,
                                                 unsigned* __restrict__ vmax) {
  const int row = blockIdx.x;
  const int tid = threadIdx.x;
  const float* x = Vb + (size_t)row * kE;
  __shared__ float r4[4];
  float am = 0.f;
#pragma unroll
  for (int it = 0; it < 2; ++it) {
    const float4 v = *reinterpret_cast<const float4*>(x + (size_t)(it * 256 + tid) * 4);
    am = fmaxf(am, fmaxf(fmaxf(fabsf(v.x), fabsf(v.y)), fmaxf(fabsf(v.z), fabsf(v.w))));
  }
  const float bm = blockMax256(am, r4);
  if (tid == 0) atomicMax(vmax, __float_as_uint(bm));
}

// k fp32 -> mixed-quant int codes as bf16 + chosen scale per row
__global__ __launch_bounds__(256) void k_kint(const float* __restrict__ Kb,
                                              const float* __restrict__ s4,
                                              const float* __restrict__ smix,
                                              const int* __restrict__ sel,
                                              short* __restrict__ ki,
                                              float* __restrict__ skg) {
  const int row = blockIdx.x;
  const int tid = threadIdx.x;
  const int t = row & (kT - 1);
  const float s = sel[t] ? smix[t] : s4[row];
  const float* x = Kb + (size_t)row * kE;
#pragma unroll
  for (int it = 0; it < 2; ++it) {
    const int i = (it * 256 + tid) * 4;
    const float4 v = *reinterpret_cast<const float4*>(x + i);
    short4 q;
    q.x = (short)bfr(rintf(v.x / s));
    q.y = (short)bfr(rintf(v.y / s));
    q.z = (short)bfr(rintf(v.z / s));
    q.w = (short)bfr(rintf(v.w / s));
    *reinterpret_cast<short4*>(ki + (size_t)row * kE + i) = q;
  }
  if (tid == 0) skg[row] = s;
}

// v fp32 -> int codes as bf16, transposed per head: vt[(bh*64+d)*1024 + t]
__global__ __launch_bounds__(256) void k_vint(const float* __restrict__ Vb,
                                              const unsigned* __restrict__ vmax,
                                              short* __restrict__ vt) {
  const int tt = blockIdx.x;
  const int bh = blockIdx.y;
  const int b = bh >> 5, h = bh & 31;
  const float sv = fmaxf(__uint_as_float(*vmax), 1e-5f) / 7.f;
  __shared__ short tr[64][80];
  const int tid = threadIdx.x;
#pragma unroll
  for (int i = 0; i < 4; ++i) {
    const int e = i * 256 + tid;
    const int tok = e >> 4, d4 = (e & 15) * 4;
    const float4 v = *reinterpret_cast<const float4*>(
        &Vb[(size_t)(b * kT + tt * 64 + tok) * kE + h * 64 + d4]);
    tr[d4 + 0][tok] = (short)bfr(rintf(v.x / sv));
    tr[d4 + 1][tok] = (short)bfr(rintf(v.y / sv));
    tr[d4 + 2][tok] = (short)bfr(rintf(v.z / sv));
    tr[d4 + 3][tok] = (short)bfr(rintf(v.w / sv));
  }
  __syncthreads();
#pragma unroll
  for (int i = 0; i < 2; ++i) {
    const int e = i * 256 + tid;
    const int d = e >> 3, u = e & 7;
    const bf16x8 row = *reinterpret_cast<const bf16x8*>(&tr[d][u * 8]);
    *reinterpret_cast<bf16x8*>(&vt[(size_t)(bh * 64 + d) * kT + tt * 64 + u * 8]) = row;
  }
}

// ---------------- int8 MFMA GEMM (shared body) ----------------
__device__ __forceinline__ void gemm_i8_body(const int8_t* __restrict__ A,
                                             const float* __restrict__ sa,
                                             const int8_t* __restrict__ Bw,
                                             const float* __restrict__ sw,
                                             const float* __restrict__ bias,
                                             float* __restrict__ Y,
                                             int8_t* As0, int8_t* As1,
                                             int8_t* Bs0, int8_t* Bs1) {
  int8_t* Asb[2] = {As0, As1};
  int8_t* Bsb[2] = {Bs0, Bs1};
  const int tid = threadIdx.x;
  const int lane = tid & 63, w = tid >> 6;
  const int g = lane >> 4, c16 = lane & 15;
  const int m0 = blockIdx.y * 128, n0 = blockIdx.x * 128;
  const int wm = (w >> 1) * 64, wn = (w & 1) * 64;

  const i32x4 zero = {0, 0, 0, 0};
  i32x4 acc[4][4];
#pragma unroll
  for (int i = 0; i < 4; ++i)
#pragma unroll
    for (int j = 0; j < 4; ++j) acc[i][j] = zero;

  const int srow = tid >> 2, su = tid & 3;
  auto stage = [&](int buf, int k0) {
#pragma unroll
    for (int i = 0; i < 2; ++i) {
      const int row = i * 64 + srow;
      const int uoff = ((su ^ (row & 3)) << 4);
      gload16(A + (size_t)(m0 + row) * kE + k0 + uoff, &Asb[buf][row * 64 + su * 16]);
      gload16(Bw + (size_t)(n0 + row) * kE + k0 + uoff, &Bsb[buf][row * 64 + su * 16]);
    }
  };

  stage(0, 0);
  __syncthreads();
  int cur = 0;
  for (int k0 = 0; k0 < kE; k0 += 64) {
    if (k0 + 64 < kE) stage(cur ^ 1, k0 + 64);
    i32x4 av[4], bv[4];
#pragma unroll
    for (int f = 0; f < 4; ++f) {
      const int ar = wm + f * 16 + c16;
      av[f] = *reinterpret_cast<const i32x4*>(&Asb[cur][ar * 64 + ((g ^ (c16 & 3)) << 4)]);
      const int br = wn + f * 16 + c16;
      bv[f] = *reinterpret_cast<const i32x4*>(&Bsb[cur][br * 64 + ((g ^ (c16 & 3)) << 4)]);
    }
#pragma unroll
    for (int fm = 0; fm < 4; ++fm)
#pragma unroll
      for (int fn = 0; fn < 4; ++fn) acc[fm][fn] = MFMA_I8(av[fm], bv[fn], acc[fm][fn]);
    __syncthreads();
    cur ^= 1;
  }

#pragma unroll
  for (int fn = 0; fn < 4; ++fn) {
    const int n = n0 + wn + fn * 16 + c16;
    const float swn = sw[n], bn = bias[n];
#pragma unroll
    for (int fm = 0; fm < 4; ++fm) {
#pragma unroll
      for (int r = 0; r < 4; ++r) {
        const int m = m0 + wm + fm * 16 + g * 4 + r;
        Y[(size_t)m * kE + n] = (float)acc[fm][fn][r] * sa[m] * swn + bn;
      }
    }
  }
}

__global__ __launch_bounds__(256) void k_gemm_i8(const int8_t* __restrict__ A,
                                                 const float* __restrict__ sa,
                                                 const int8_t* __restrict__ Bw,
                                                 const float* __restrict__ sw,
                                                 const float* __restrict__ bias,
                                                 float* __restrict__ Y) {
  __shared__ int8_t As[2][128 * 64];
  __shared__ int8_t Bs[2][128 * 64];
  gemm_i8_body(A, sa, Bw, sw, bias, Y, As[0], As[1], Bs[0], Bs[1]);
}

// fused Q/K/V projections; blockIdx.z selects weight/bias/output
__global__ __launch_bounds__(256) void k_gemm_qkv(const int8_t* __restrict__ A,
                                                  const float* __restrict__ sa,
                                                  const int8_t* __restrict__ Wq,
                                                  const int8_t* __restrict__ Wk,
                                                  const int8_t* __restrict__ Wv,
                                                  const float* __restrict__ sWall,
                                                  const float* __restrict__ bq,
                                                  const float* __restrict__ bk,
                                                  const float* __restrict__ bv,
                                                  float* __restrict__ qb,
                                                  float* __restrict__ kb,
                                                  float* __restrict__ vb) {
  __shared__ int8_t As[2][128 * 64];
  __shared__ int8_t Bs[2][128 * 64];
  const int z = blockIdx.z;
  const int8_t* Bw = (z == 0) ? Wq : (z == 1) ? Wk : Wv;
  const float* sw = sWall + (size_t)z * kE;
  const float* bias = (z == 0) ? bq : (z == 1) ? bk : bv;
  float* Y = (z == 0) ? qb : (z == 1) ? kb : vb;
  gemm_i8_body(A, sa, Bw, sw, bias, Y, As[0], As[1], Bs[0], Bs[1]);
}

// ---------------- attention pass 1 (paired q-tiles r1 and 15-r1) ----------------
__global__ __launch_bounds__(256) void k_attn1(const short* __restrict__ qi,
                                               const short* __restrict__ khi,
                                               const short* __restrict__ klo,
                                               const float* __restrict__ sqg,
                                               float* __restrict__ accPart) {
  const int r1 = blockIdx.x, r2 = 15 - r1, bh = blockIdx.y;
  const int b = bh >> 5, h = bh & 31;
  const int tid = threadIdx.x, lane = tid & 63, w = tid >> 6;
  const int g = lane >> 4, c16 = lane & 15;
  const int swz = c16 & 7;

  __shared__ short qs1[64 * 64];
  __shared__ short qs2[64 * 64];
  __shared__ short hbuf[2][64 * 64];
  __shared__ short lbuf[2][64 * 64];
  __shared__ float accL[1024];
  __shared__ float Arow[128], Crow[128];

  for (int i = tid; i < 1024; i += 256) accL[i] = 0.f;

  const int st8 = tid >> 3, su = tid & 7;
  {
    const int tokb1 = b * kT + r1 * 64;
    const int tokb2 = b * kT + r2 * 64;
#pragma unroll
    for (int i = 0; i < 2; ++i) {
      const int tok = i * 32 + st8;
      const int co = ((su ^ (tok & 7)) << 3);
      gload16(qi + (size_t)(tokb1 + tok) * kE + h * 64 + co, &qs1[tok * 64 + su * 8]);
      gload16(qi + (size_t)(tokb2 + tok) * kE + h * 64 + co, &qs2[tok * 64 + su * 8]);
    }
  }
  auto stage = [&](int buf, int kt) {
    const int tokb = b * kT + kt * 64;
#pragma unroll
    for (int i = 0; i < 2; ++i) {
      const int tok = i * 32 + st8;
      const size_t gsrc = (size_t)(tokb + tok) * kE + h * 64 + ((su ^ (tok & 7)) << 3);
      gload16(khi + gsrc, &hbuf[buf][tok * 64 + su * 8]);
      gload16(klo + gsrc, &lbuf[buf][tok * 64 + su * 8]);
    }
  };

  stage(0, 0);
  __syncthreads();

  // ---- phase A: row stats for both q-tiles (S^T = K*Q) ----
  const int qrow = w * 16 + c16;
  const bf16x8 q1_0 = *reinterpret_cast<const bf16x8*>(&qs1[qrow * 64 + ((g ^ swz) << 3)]);
  const bf16x8 q1_1 = *reinterpret_cast<const bf16x8*>(&qs1[qrow * 64 + (((4 + g) ^ swz) << 3)]);
  const bf16x8 q2_0 = *reinterpret_cast<const bf16x8*>(&qs2[qrow * 64 + ((g ^ swz) << 3)]);
  const bf16x8 q2_1 = *reinterpret_cast<const bf16x8*>(&qs2[qrow * 64 + (((4 + g) ^ swz) << 3)]);
  const float A1c = sqg[b * kT + r1 * 64 + qrow] * L2E;
  const float A2c = sqg[b * kT + r2 * 64 + qrow] * L2E;

  float m1 = NEG_INF, l1 = 0.f, m2_ = NEG_INF, l2 = 0.f;
  int cur = 0;

  for (int kt = 0; kt <= r2; ++kt) {
    if (kt < r2) stage(cur ^ 1, kt + 1);
    const bool act1 = kt <= r1;
    float p1[4][4], p2[4][4];
    float pm1 = NEG_INF, pm2 = NEG_INF;
#pragma unroll
    for (int f = 0; f < 4; ++f) {
      const int tokl = f * 16 + c16;
      const bf16x8 ah0 = *reinterpret_cast<const bf16x8*>(&hbuf[cur][tokl * 64 + ((g ^ swz) << 3)]);
      const bf16x8 ah1 = *reinterpret_cast<const bf16x8*>(&hbuf[cur][tokl * 64 + (((4 + g) ^ swz) << 3)]);
      const bf16x8 al0 = *reinterpret_cast<const bf16x8*>(&lbuf[cur][tokl * 64 + ((g ^ swz) << 3)]);
      const bf16x8 al1 = *reinterpret_cast<const bf16x8*>(&lbuf[cur][tokl * 64 + (((4 + g) ^ swz) << 3)]);
      f32x4 sB = {0.f, 0.f, 0.f, 0.f};
      sB = MFMA_BF16(ah0, q2_0, sB);
      sB = MFMA_BF16(ah1, q2_1, sB);
      sB = MFMA_BF16(al0, q2_0, sB);
      sB = MFMA_BF16(al1, q2_1, sB);
      f32x4 sA = {0.f, 0.f, 0.f, 0.f};
      if (act1) {
        sA = MFMA_BF16(ah0, q1_0, sA);
        sA = MFMA_BF16(ah1, q1_1, sA);
        sA = MFMA_BF16(al0, q1_0, sA);
        sA = MFMA_BF16(al1, q1_1, sA);
      }
#pragma unroll
      for (int r = 0; r < 4; ++r) {
        const int tokd = f * 16 + g * 4 + r;
        float s2 = sB[r] * A2c;
        if (kt == r2 && tokd > qrow) s2 = NEG_INF;
        p2[f][r] = s2;
        pm2 = fmaxf(pm2, s2);
        float s1 = sA[r] * A1c;
        if (kt == r1 && tokd > qrow) s1 = NEG_INF;
        p1[f][r] = s1;
        pm1 = fmaxf(pm1, s1);
      }
    }
    {
      pm2 = fmaxf(pm2, __shfl_xor(pm2, 16));
      pm2 = fmaxf(pm2, __shfl_xor(pm2, 32));
      const bool upd = pm2 > m2_ + 8.f;
      const float mn = upd ? fmaxf(m2_, pm2) : m2_;
      const float fsc = fexp2(m2_ - mn);
      float rs = 0.f;
#pragma unroll
      for (int f = 0; f < 4; ++f)
#pragma unroll
        for (int r = 0; r < 4; ++r) rs += fexp2(p2[f][r] - mn);
      rs += __shfl_xor(rs, 16);
      rs += __shfl_xor(rs, 32);
      l2 = l2 * fsc + rs;
      m2_ = mn;
    }
    if (act1) {
      pm1 = fmaxf(pm1, __shfl_xor(pm1, 16));
      pm1 = fmaxf(pm1, __shfl_xor(pm1, 32));
      const bool upd = pm1 > m1 + 8.f;
      const float mn = upd ? fmaxf(m1, pm1) : m1;
      const float fsc = fexp2(m1 - mn);
      float rs = 0.f;
#pragma unroll
      for (int f = 0; f < 4; ++f)
#pragma unroll
        for (int r = 0; r < 4; ++r) rs += fexp2(p1[f][r] - mn);
      rs += __shfl_xor(rs, 16);
      rs += __shfl_xor(rs, 32);
      l1 = l1 * fsc + rs;
      m1 = mn;
    }
    __syncthreads();
    cur ^= 1;
  }

  if (g == 0) {
    Arow[qrow] = A1c;
    Crow[qrow] = -(m1 + __builtin_amdgcn_logf(l1));
    Arow[64 + qrow] = A2c;
    Crow[64 + qrow] = -(m2_ + __builtin_amdgcn_logf(l2));
  }
  stage(0, 0);
  __syncthreads();

  // ---- phase B: normalized column sums (S = Q*K), both q-tiles ----
  bf16x8 qa1_0[4], qa1_1[4], qa2_0[4], qa2_1[4];
  float Ar1[4][4], Cr1[4][4], Ar2[4][4], Cr2[4][4];
#pragma unroll
  for (int f = 0; f < 4; ++f) {
    const int qr = f * 16 + c16;
    qa1_0[f] = *reinterpret_cast<const bf16x8*>(&qs1[qr * 64 + ((g ^ swz) << 3)]);
    qa1_1[f] = *reinterpret_cast<const bf16x8*>(&qs1[qr * 64 + (((4 + g) ^ swz) << 3)]);
    qa2_0[f] = *reinterpret_cast<const bf16x8*>(&qs2[qr * 64 + ((g ^ swz) << 3)]);
    qa2_1[f] = *reinterpret_cast<const bf16x8*>(&qs2[qr * 64 + (((4 + g) ^ swz) << 3)]);
#pragma unroll
    for (int r = 0; r < 4; ++r) {
      const int tokd = f * 16 + g * 4 + r;
      Ar1[f][r] = Arow[tokd];
      Cr1[f][r] = Crow[tokd];
      Ar2[f][r] = Arow[64 + tokd];
      Cr2[f][r] = Crow[64 + tokd];
    }
  }

  const int ktokL = w * 16 + c16;
  cur = 0;
  for (int kt = 0; kt <= r2; ++kt) {
    if (kt < r2) stage(cur ^ 1, kt + 1);
    const bf16x8 kh0 = *reinterpret_cast<const bf16x8*>(&hbuf[cur][ktokL * 64 + ((g ^ swz) << 3)]);
    const bf16x8 kh1 = *reinterpret_cast<const bf16x8*>(&hbuf[cur][ktokL * 64 + (((4 + g) ^ swz) << 3)]);
    const bf16x8 kl0 = *reinterpret_cast<const bf16x8*>(&lbuf[cur][ktokL * 64 + ((g ^ swz) << 3)]);
    const bf16x8 kl1 = *reinterpret_cast<const bf16x8*>(&lbuf[cur][ktokL * 64 + (((4 + g) ^ swz) << 3)]);
    float csum = 0.f;
    // tile 2 (always active)
    if (kt < r2) {
#pragma unroll
      for (int f = 0; f < 4; ++f) {
        f32x4 sf = {0.f, 0.f, 0.f, 0.f};
        sf = MFMA_BF16(qa2_0[f], kh0, sf);
        sf = MFMA_BF16(qa2_1[f], kh1, sf);
        sf = MFMA_BF16(qa2_0[f], kl0, sf);
        sf = MFMA_BF16(qa2_1[f], kl1, sf);
#pragma unroll
        for (int r = 0; r < 4; ++r) csum += fexp2(fmaf(sf[r], Ar2[f][r], Cr2[f][r]));
      }
    } else {
#pragma unroll
      for (int f = 0; f < 4; ++f) {
        f32x4 sf = {0.f, 0.f, 0.f, 0.f};
        sf = MFMA_BF16(qa2_0[f], kh0, sf);
        sf = MFMA_BF16(qa2_1[f], kh1, sf);
        sf = MFMA_BF16(qa2_0[f], kl0, sf);
        sf = MFMA_BF16(qa2_1[f], kl1, sf);
#pragma unroll
        for (int r = 0; r < 4; ++r) {
          const float v = fexp2(fmaf(sf[r], Ar2[f][r], Cr2[f][r]));
          if (ktokL <= (f * 16 + g * 4 + r)) csum += v;
        }
      }
    }
    if (kt <= r1) {
      if (kt < r1) {
#pragma unroll
        for (int f = 0; f < 4; ++f) {
          f32x4 sf = {0.f, 0.f, 0.f, 0.f};
          sf = MFMA_BF16(qa1_0[f], kh0, sf);
          sf = MFMA_BF16(qa1_1[f], kh1, sf);
          sf = MFMA_BF16(qa1_0[f], kl0, sf);
          sf = MFMA_BF16(qa1_1[f], kl1, sf);
#pragma unroll
          for (int r = 0; r < 4; ++r) csum += fexp2(fmaf(sf[r], Ar1[f][r], Cr1[f][r]));
        }
      } else {
#pragma unroll
        for (int f = 0; f < 4; ++f) {
          f32x4 sf = {0.f, 0.f, 0.f, 0.f};
          sf = MFMA_BF16(qa1_0[f], kh0, sf);
          sf = MFMA_BF16(qa1_1[f], kh1, sf);
          sf = MFMA_BF16(qa1_0[f], kl0, sf);
          sf = MFMA_BF16(qa1_1[f], kl1, sf);
#pragma unroll
          for (int r = 0; r < 4; ++r) {
            const float v = fexp2(fmaf(sf[r], Ar1[f][r], Cr1[f][r]));
            if (ktokL <= (f * 16 + g * 4 + r)) csum += v;
          }
        }
      }
    }
    csum += __shfl_xor(csum, 16);
    csum += __shfl_xor(csum, 32);
    if (g == 0) accL[kt * 64 + ktokL] += csum;
    __syncthreads();
    cur ^= 1;
  }

  for (int i = tid; i < 1024; i += 256)
    accPart[(size_t)(bh * 8 + r1) * 1024 + i] = accL[i];
}

__global__ __launch_bounds__(256) void k_accreduce(const float* __restrict__ part,
                                                   float* __restrict__ acc) {
  const int j = blockIdx.x;
  const int tid = threadIdx.x;
  float s = 0.f;
  for (int p = tid; p < 512; p += 256) s += part[(size_t)p * 1024 + j];
  __shared__ float r4[4];
  const float ws = waveReduceSum(s);
  if ((tid & 63) == 0) r4[tid >> 6] = ws;
  __syncthreads();
  if (tid == 0) {
    const float t = r4[0] + r4[1] + r4[2] + r4[3];
    acc[j] = t / (float)(kT - j) / 64.f;
  }
}

__global__ __launch_bounds__(256) void k_topk(const float* __restrict__ acc,
                                              int* __restrict__ sel) {
  const int gq = blockIdx.x;
  const int i = threadIdx.x;
  __shared__ float v[256];
  const float vi = acc[gq * 256 + i];
  v[i] = vi;
  __syncthreads();
  int rank = 0;
  for (int j = 0; j < 256; ++j) {
    const float vj = v[j];
    rank += (vj > vi) || (vj == vi && j < i);
  }
  sel[gq * 256 + i] = (rank < 128) ? 1 : 0;
}

// ---------------- attention pass 2 (paired flash, single-bf16 P) ----------------
__global__ __launch_bounds__(256) void k_attn2(const short* __restrict__ qi,
                                               const short* __restrict__ ki,
                                               const short* __restrict__ vt,
                                               const float* __restrict__ sqg,
                                               const float* __restrict__ skg,
                                               const unsigned* __restrict__ vmax,
                                               float* __restrict__ ctx) {
  const int r1 = blockIdx.x, r2 = 15 - r1, bh = blockIdx.y;
  const int b = bh >> 5, h = bh & 31;
  const int tid = threadIdx.x, lane = tid & 63, w = tid >> 6;
  const int g = lane >> 4, c16 = lane & 15;
  const int swz = c16 & 7;
  const int wrow = w * 16 + c16;

  __shared__ short kbuf[2][64 * 64];
  __shared__ short vbuf[2][64 * 64];
  __shared__ float skl[2][64];

  const int qtokA = b * kT + r1 * 64 + wrow;
  const int qtokB = b * kT + r2 * 64 + wrow;
  bf16x8 qfA[2], qfB[2];
  qfA[0] = *reinterpret_cast<const bf16x8*>(qi + (size_t)qtokA * kE + h * 64 + g * 8);
  qfA[1] = *reinterpret_cast<const bf16x8*>(qi + (size_t)qtokA * kE + h * 64 + 32 + g * 8);
  qfB[0] = *reinterpret_cast<const bf16x8*>(qi + (size_t)qtokB * kE + h * 64 + g * 8);
  qfB[1] = *reinterpret_cast<const bf16x8*>(qi + (size_t)qtokB * kE + h * 64 + 32 + g * 8);
  const float sqA = sqg[qtokA] * L2E;
  const float sqB = sqg[qtokB] * L2E;
  const float sv = fmaxf(__uint_as_float(*vmax), 1e-5f) / 7.f;

  const int st8 = tid >> 3, su = tid & 7;
  auto stage = [&](int buf, int kt) {
    const int tokb = b * kT + kt * 64;
#pragma unroll
    for (int i = 0; i < 2; ++i) {
      const int tok = i * 32 + st8;
      gload16(ki + (size_t)(tokb + tok) * kE + h * 64 + ((su ^ (tok & 7)) << 3),
              &kbuf[buf][tok * 64 + su * 8]);
      gload16(vt + (size_t)(bh * 64 + tok) * kT + kt * 64 + ((su ^ (tok & 7)) << 3),
              &vbuf[buf][tok * 64 + su * 8]);
    }
    if (tid < 64) skl[buf][tid] = skg[tokb + tid];
  };

  float mA = NEG_INF, lA = 0.f, mB = NEG_INF, lB = 0.f;
  f32x4 otA[4], otB[4];
#pragma unroll
  for (int f = 0; f < 4; ++f) {
    otA[f] = (f32x4){0.f, 0.f, 0.f, 0.f};
    otB[f] = (f32x4){0.f, 0.f, 0.f, 0.f};
  }

  stage(0, 0);
  __syncthreads();
  int cur = 0;

  const int srcLo = c16 | ((g & 1) << 5);
  const int srcHi = srcLo | 16;
  const bool selq = ((g >> 1) & 1) != 0;

  for (int kt = 0; kt <= r2; ++kt) {
    if (kt < r2) stage(cur ^ 1, kt + 1);
    const bool act1 = kt <= r1;

    f32x4 sfB4[4], sfA4[4];
#pragma unroll
    for (int f = 0; f < 4; ++f) {
      const int tokl = f * 16 + c16;
      const bf16x8 k0 = *reinterpret_cast<const bf16x8*>(&kbuf[cur][tokl * 64 + ((g ^ swz) << 3)]);
      const bf16x8 k1 = *reinterpret_cast<const bf16x8*>(&kbuf[cur][tokl * 64 + (((4 + g) ^ swz) << 3)]);
      f32x4 s = {0.f, 0.f, 0.f, 0.f};
      s = MFMA_BF16(k0, qfB[0], s);
      s = MFMA_BF16(k1, qfB[1], s);
      sfB4[f] = s;
      f32x4 sa = {0.f, 0.f, 0.f, 0.f};
      if (act1) {
        sa = MFMA_BF16(k0, qfA[0], sa);
        sa = MFMA_BF16(k1, qfA[1], sa);
      }
      sfA4[f] = sa;
    }

    // ---- tile B softmax + PV ----
    {
      float p[4][4];
      float pm = NEG_INF;
#pragma unroll
      for (int f = 0; f < 4; ++f)
#pragma unroll
        for (int r = 0; r < 4; ++r) {
          const int tokd = f * 16 + g * 4 + r;
          float s2 = sfB4[f][r] * skl[cur][tokd] * sqB;
          if (kt == r2 && tokd > wrow) s2 = NEG_INF;
          p[f][r] = s2;
          pm = fmaxf(pm, s2);
        }
      pm = fmaxf(pm, __shfl_xor(pm, 16));
      pm = fmaxf(pm, __shfl_xor(pm, 32));
      const bool upd = pm > mB + 8.f;
      const float mn = upd ? fmaxf(mB, pm) : mB;
      const float fsc = fexp2(mB - mn);
      mB = mn;
      float rs = 0.f;
#pragma unroll
      for (int f = 0; f < 4; ++f)
#pragma unroll
        for (int r = 0; r < 4; ++r) {
          const float e = fexp2(p[f][r] - mn);
          p[f][r] = e;
          rs += e;
        }
      rs += __shfl_xor(rs, 16);
      rs += __shfl_xor(rs, 32);
      lB = lB * fsc + rs;
      if (__any(upd)) {
#pragma unroll
        for (int f = 0; f < 4; ++f)
#pragma unroll
          for (int r = 0; r < 4; ++r) otB[f][r] *= fsc;
      }
#pragma unroll
      for (int c = 0; c < 2; ++c) {
        const unsigned q0a = pk2(p[2 * c][0], p[2 * c][1]);
        const unsigned q0b = pk2(p[2 * c][2], p[2 * c][3]);
        const unsigned q1a = pk2(p[2 * c + 1][0], p[2 * c + 1][1]);
        const unsigned q1b = pk2(p[2 * c + 1][2], p[2 * c + 1][3]);
        unsigned a0, a1;
        union { unsigned u[4]; bf16x8 v; } Bh;
        a0 = __shfl(q0a, srcLo); a1 = __shfl(q1a, srcLo); Bh.u[0] = selq ? a1 : a0;
        a0 = __shfl(q0b, srcLo); a1 = __shfl(q1b, srcLo); Bh.u[1] = selq ? a1 : a0;
        a0 = __shfl(q0a, srcHi); a1 = __shfl(q1a, srcHi); Bh.u[2] = selq ? a1 : a0;
        a0 = __shfl(q0b, srcHi); a1 = __shfl(q1b, srcHi); Bh.u[3] = selq ? a1 : a0;
#pragma unroll
        for (int fd = 0; fd < 4; ++fd) {
          const int d = fd * 16 + c16;
          const bf16x8 va = *reinterpret_cast<const bf16x8*>(
              &vbuf[cur][d * 64 + ((((c << 2) | g) ^ swz) << 3)]);
          otB[fd] = MFMA_BF16(va, Bh.v, otB[fd]);
        }
      }
    }

    // ---- tile A softmax + PV (gated) ----
    if (act1) {
      float p[4][4];
      float pm = NEG_INF;
#pragma unroll
      for (int f = 0; f < 4; ++f)
#pragma unroll
        for (int r = 0; r < 4; ++r) {
          const int tokd = f * 16 + g * 4 + r;
          float s2 = sfA4[f][r] * skl[cur][tokd] * sqA;
          if (kt == r1 && tokd > wrow) s2 = NEG_INF;
          p[f][r] = s2;
          pm = fmaxf(pm, s2);
        }
      pm = fmaxf(pm, __shfl_xor(pm, 16));
      pm = fmaxf(pm, __shfl_xor(pm, 32));
      const bool upd = pm > mA + 8.f;
      const float mn = upd ? fmaxf(mA, pm) : mA;
      const float fsc = fexp2(mA - mn);
      mA = mn;
      float rs = 0.f;
#pragma unroll
      for (int f = 0; f < 4; ++f)
#pragma unroll
        for (int r = 0; r < 4; ++r) {
          const float e = fexp2(p[f][r] - mn);
          p[f][r] = e;
          rs += e;
        }
      rs += __shfl_xor(rs, 16);
      rs += __shfl_xor(rs, 32);
      lA = lA * fsc + rs;
      if (__any(upd)) {
#pragma unroll
        for (int f = 0; f < 4; ++f)
#pragma unroll
          for (int r = 0; r < 4; ++r) otA[f][r] *= fsc;
      }
#pragma unroll
      for (int c = 0; c < 2; ++c) {
        const unsigned q0a = pk2(p[2 * c][0], p[2 * c][1]);
        const unsigned q0b = pk2(p[2 * c][2], p[2 * c][3]);
        const unsigned q1a = pk2(p[2 * c + 1][0], p[2 * c + 1][1]);
        const unsigned q1b = pk2(p[2 * c + 1][2], p[2 * c + 1][3]);
        unsigned a0, a1;
        union { unsigned u[4]; bf16x8 v; } Bh;
        a0 = __shfl(q0a, srcLo); a1 = __shfl(q1a, srcLo); Bh.u[0] = selq ? a1 : a0;
        a0 = __shfl(q0b, srcLo); a1 = __shfl(q1b, srcLo); Bh.u[1] = selq ? a1 : a0;
        a0 = __shfl(q0a, srcHi); a1 = __shfl(q1a, srcHi); Bh.u[2] = selq ? a1 : a0;
        a0 = __shfl(q0b, srcHi); a1 = __shfl(q1b, srcHi); Bh.u[3] = selq ? a1 : a0;
#pragma unroll
        for (int fd = 0; fd < 4; ++fd) {
          const int d = fd * 16 + c16;
          const bf16x8 va = *reinterpret_cast<const bf16x8*>(
              &vbuf[cur][d * 64 + ((((c << 2) | g) ^ swz) << 3)]);
          otA[fd] = MFMA_BF16(va, Bh.v, otA[fd]);
        }
      }
    }

    __syncthreads();
    cur ^= 1;
  }

  const float ilA = sv / lA;
  const float ilB = sv / lB;
#pragma unroll
  for (int fd = 0; fd < 4; ++fd) {
    float4 oA, oB;
    oA.x = otA[fd][0] * ilA; oA.y = otA[fd][1] * ilA;
    oA.z = otA[fd][2] * ilA; oA.w = otA[fd][3] * ilA;
    oB.x = otB[fd][0] * ilB; oB.y = otB[fd][1] * ilB;
    oB.z = otB[fd][2] * ilB; oB.w = otB[fd][3] * ilB;
    *reinterpret_cast<float4*>(&ctx[(size_t)qtokA * kE + h * 64 + fd * 16 + g * 4]) = oA;
    *reinterpret_cast<float4*>(&ctx[(size_t)qtokB * kE + h * 64 + fd * 16 + g * 4]) = oB;
  }
}

// ---------------- launcher ----------------
extern "C" void kernel_launch(void* const* d_in, const int* in_sizes, int n_in,
                              void* d_out, int out_size, void* d_ws, size_t ws_size,
                              hipStream_t stream) {
  (void)in_sizes; (void)n_in; (void)out_size; (void)ws_size;
  const float* hs = (const float*)d_in[0];
  const float* Wq = (const float*)d_in[2];
  const float* bq = (const float*)d_in[3];
  const float* Wk = (const float*)d_in[4];
  const float* bk = (const float*)d_in[5];
  const float* Wv = (const float*)d_in[6];
  const float* bv = (const float*)d_in[7];
  const float* Wo = (const float*)d_in[8];
  const float* bo = (const float*)d_in[9];
  float* out = (float*)d_out;

  char* p = (char*)d_ws;
  auto take = [&](size_t bytes) {
    char* r = p;
    p += (bytes + 255) & ~(size_t)255;
    return r;
  };
  float* qb  = (float*)take((size_t)2048 * 2048 * 4);  // later khi+klo -> kint+vt
  float* kb  = (float*)take((size_t)2048 * 2048 * 4);
  float* vb  = (float*)take((size_t)2048 * 2048 * 4);
  float* ctx = (float*)take((size_t)2048 * 2048 * 4);  // accPart(2MB) + wq/wk/wv(12MB) alias
  short* qiB = (short*)take((size_t)2048 * 2048 * 2);
  int8_t* xq  = (int8_t*)take((size_t)2048 * 2048);
  int8_t* woq = (int8_t*)take((size_t)2048 * 2048);
  float* sX    = (float*)take(2048 * 4);
  float* sWall = (float*)take(4 * 2048 * 4);
  float* sC    = (float*)take(2048 * 4);
  float* s4v   = (float*)take(2048 * 4);
  float* smix  = (float*)take(1024 * 4);
  float* accv  = (float*)take(1024 * 4);
  int*   sel   = (int*)take(1024 * 4);
  float* sqg   = (float*)take(2048 * 4);
  float* skg   = (float*)take(2048 * 4);
  unsigned* vmax = (unsigned*)take(256);

  // aliases
  short* khi = (short*)qb;
  short* klo = (short*)qb + (size_t)2048 * 2048;
  short* kint = khi;
  short* vtp  = klo;
  float* accPart = ctx;                                  // 512*1024*4 = 2MB
  int8_t* wqq = (int8_t*)ctx + ((size_t)2 << 20);        // weights parked in ctx region
  int8_t* wkq = (int8_t*)ctx + ((size_t)6 << 20);
  int8_t* wvq = (int8_t*)ctx + ((size_t)10 << 20);
  int8_t* cq = xq;

  k_rowquant_i8<<<2048, 256, 0, stream>>>(hs, xq, sX);
  k_rowquant_w4<<<dim3(2048, 4), 256, 0, stream>>>(Wq, Wk, Wv, Wo, wqq, wkq, wvq, woq, sWall);

  k_gemm_qkv<<<dim3(16, 16, 3), 256, 0, stream>>>(xq, sX, wqq, wkq, wvq, sWall,
                                                  bq, bk, bv, qb, kb, vb);

  k_q2int<<<2048, 256, 0, stream>>>(qb, qiB, sqg);
  k_ksplitscale<<<2048, 256, 0, stream>>>(kb, khi, klo, s4v, smix);
  k_init<<<1, 64, 0, stream>>>(vmax);
  k_vabsmax<<<2048, 256, 0, stream>>>(vb, vmax);

  k_attn1<<<dim3(8, 64), 256, 0, stream>>>(qiB, khi, klo, sqg, accPart);
  k_accreduce<<<1024, 256, 0, stream>>>(accPart, accv);
  k_topk<<<4, 256, 0, stream>>>(accv, sel);

  k_kint<<<2048, 256, 0, stream>>>(kb, s4v, smix, sel, kint, skg);
  k_vint<<<dim3(16, 64), 256, 0, stream>>>(vb, vmax, vtp);

  k_attn2<<<dim3(8, 64), 256, 0, stream>>>(qiB, kint, vtp, sqg, skg, vmax, ctx);

  k_rowquant_i8<<<2048, 256, 0, stream>>>(ctx, cq, sC);
  k_gemm_i8<<<dim3(16, 16), 256, 0, stream>>>(cq, sC, woq, sWall + 3 * 2048, bo, out);
}

// Round 5
// 232.582 us; speedup vs baseline: 7.3054x; 1.0951x over previous
//
#include <hip/hip_runtime.h>
#include <stdint.h>

#define NEG_INF (-__builtin_inff())
#define L2E 1.4426950408889634f

namespace {
constexpr int kT   = 1024;
constexpr int kE   = 2048;
}

using bf16x8 = __attribute__((ext_vector_type(8))) short;
using f32x4  = __attribute__((ext_vector_type(4))) float;
using i32x4  = __attribute__((ext_vector_type(4))) int;

#define MFMA_BF16(a, b, c) __builtin_amdgcn_mfma_f32_16x16x32_bf16((a), (b), (c), 0, 0, 0)
#define MFMA_I8(a, b, c)   __builtin_amdgcn_mfma_i32_16x16x64_i8((a), (b), (c), 0, 0, 0)

// ---------------- small helpers ----------------
__device__ __forceinline__ void gload16(const void* g, void* l) {
  __builtin_amdgcn_global_load_lds((const __attribute__((address_space(1))) unsigned*)g,
                                   (__attribute__((address_space(3))) unsigned*)l, 16, 0, 0);
}
__device__ __forceinline__ unsigned bfr(float x) {  // f32 -> bf16 bits (RNE)
  unsigned u = __float_as_uint(x);
  return (u + 0x7FFFu + ((u >> 16) & 1u)) >> 16;
}
__device__ __forceinline__ float bf2f(unsigned h) { return __uint_as_float(h << 16); }
__device__ __forceinline__ unsigned pk2(float a, float b) { return bfr(a) | (bfr(b) << 16); }
__device__ __forceinline__ float fexp2(float x) { return __builtin_amdgcn_exp2f(x); }

__device__ __forceinline__ float waveReduceMax(float v) {
#pragma unroll
  for (int o = 32; o > 0; o >>= 1) v = fmaxf(v, __shfl_down(v, o, 64));
  return v;
}
__device__ __forceinline__ float waveReduceSum(float v) {
#pragma unroll
  for (int o = 32; o > 0; o >>= 1) v += __shfl_down(v, o, 64);
  return v;
}
__device__ __forceinline__ float blockMax256(float v, float* r4) {
  const int tid = threadIdx.x;
  float wm = waveReduceMax(v);
  if ((tid & 63) == 0) r4[tid >> 6] = wm;
  __syncthreads();
  float bm = fmaxf(fmaxf(r4[0], r4[1]), fmaxf(r4[2], r4[3]));
  __syncthreads();
  return bm;
}

// ---------------- fused row-quant: hs + 4 weights (grid 2048 x 5) ----------------
__global__ __launch_bounds__(256) void k_rowquant_all(const float* __restrict__ Xh,
                                                      const float* __restrict__ W0,
                                                      const float* __restrict__ W1,
                                                      const float* __restrict__ W2,
                                                      const float* __restrict__ W3,
                                                      int8_t* __restrict__ Qh,
                                                      int8_t* __restrict__ Q0,
                                                      int8_t* __restrict__ Q1,
                                                      int8_t* __restrict__ Q2,
                                                      int8_t* __restrict__ Q3,
                                                      float* __restrict__ sX,
                                                      float* __restrict__ sWall,
                                                      unsigned* __restrict__ vmax) {
  const int y = blockIdx.y;
  const float* X = (y == 0) ? Xh : (y == 1) ? W0 : (y == 2) ? W1 : (y == 3) ? W2 : W3;
  int8_t* Qp = (y == 0) ? Qh : (y == 1) ? Q0 : (y == 2) ? Q1 : (y == 3) ? Q2 : Q3;
  const int row = blockIdx.x;
  const int tid = threadIdx.x;
  if (row == 0 && y == 0 && tid == 0) *vmax = 0u;  // init for later atomicMax
  const float* x = X + (size_t)row * kE;
  __shared__ float r4[4];
  float am = 0.f;
  float4 v[2];
#pragma unroll
  for (int it = 0; it < 2; ++it) {
    v[it] = *reinterpret_cast<const float4*>(x + (size_t)(it * 256 + tid) * 4);
    am = fmaxf(am, fmaxf(fmaxf(fabsf(v[it].x), fabsf(v[it].y)), fmaxf(fabsf(v[it].z), fabsf(v[it].w))));
  }
  const float bm = blockMax256(am, r4);
  const float s = fmaxf(bm, 1e-5f) / 127.f;
  int8_t* xq = Qp + (size_t)row * kE;
#pragma unroll
  for (int it = 0; it < 2; ++it) {
    const int i = (it * 256 + tid) * 4;
    char4 q;
    q.x = (char)(int)rintf(v[it].x / s);
    q.y = (char)(int)rintf(v[it].y / s);
    q.z = (char)(int)rintf(v[it].z / s);
    q.w = (char)(int)rintf(v[it].w / s);
    *reinterpret_cast<char4*>(xq + i) = q;
  }
  if (tid == 0) {
    if (y == 0) sX[row] = s;
    else sWall[(y - 1) * kE + row] = s;
  }
}

// final-context row quant (kept separate: runs after attn2)
__global__ __launch_bounds__(256) void k_rowquant_i8(const float* __restrict__ X,
                                                     int8_t* __restrict__ Xq,
                                                     float* __restrict__ S) {
  const int row = blockIdx.x;
  const int tid = threadIdx.x;
  const float* x = X + (size_t)row * kE;
  __shared__ float r4[4];
  float am = 0.f;
  float4 v[2];
#pragma unroll
  for (int it = 0; it < 2; ++it) {
    v[it] = *reinterpret_cast<const float4*>(x + (size_t)(it * 256 + tid) * 4);
    am = fmaxf(am, fmaxf(fmaxf(fabsf(v[it].x), fabsf(v[it].y)), fmaxf(fabsf(v[it].z), fabsf(v[it].w))));
  }
  const float bm = blockMax256(am, r4);
  const float s = fmaxf(bm, 1e-5f) / 127.f;
  int8_t* xq = Xq + (size_t)row * kE;
#pragma unroll
  for (int it = 0; it < 2; ++it) {
    const int i = (it * 256 + tid) * 4;
    char4 q;
    q.x = (char)(int)rintf(v[it].x / s);
    q.y = (char)(int)rintf(v[it].y / s);
    q.z = (char)(int)rintf(v[it].z / s);
    q.w = (char)(int)rintf(v[it].w / s);
    *reinterpret_cast<char4*>(xq + i) = q;
  }
  if (tid == 0) S[row] = s;
}

// ---------------- fused prep: q->int-bf16, k->hi/lo split + scales, v absmax ----------------
__global__ __launch_bounds__(256) void k_prep(const float* __restrict__ Qb,
                                              const float* __restrict__ Kb,
                                              const float* __restrict__ Vb,
                                              short* __restrict__ qi,
                                              float* __restrict__ sqg,
                                              short* __restrict__ khi,
                                              short* __restrict__ klo,
                                              float* __restrict__ s4,
                                              float* __restrict__ smix,
                                              unsigned* __restrict__ vmax) {
  const int row = blockIdx.x;
  const int tid = threadIdx.x;
  __shared__ float r4[4];

  // ---- q ----
  {
    const float* x = Qb + (size_t)row * kE;
    float am = 0.f;
    float4 v[2];
#pragma unroll
    for (int it = 0; it < 2; ++it) {
      v[it] = *reinterpret_cast<const float4*>(x + (size_t)(it * 256 + tid) * 4);
      am = fmaxf(am, fmaxf(fmaxf(fabsf(v[it].x), fabsf(v[it].y)), fmaxf(fabsf(v[it].z), fabsf(v[it].w))));
    }
    const float bm = blockMax256(am, r4);
    const float s = fmaxf(bm, 1e-5f) / 127.f;
#pragma unroll
    for (int it = 0; it < 2; ++it) {
      const int i = (it * 256 + tid) * 4;
      short4 q;
      q.x = (short)bfr(rintf(v[it].x / s));
      q.y = (short)bfr(rintf(v[it].y / s));
      q.z = (short)bfr(rintf(v[it].z / s));
      q.w = (short)bfr(rintf(v[it].w / s));
      *reinterpret_cast<short4*>(qi + (size_t)row * kE + i) = q;
    }
    if (tid == 0) sqg[row] = s * 0.125f;
  }

  // ---- k ----
  {
    const float* x = Kb + (size_t)row * kE;
    float am = 0.f;
    float4 v[2];
#pragma unroll
    for (int it = 0; it < 2; ++it) {
      v[it] = *reinterpret_cast<const float4*>(x + (size_t)(it * 256 + tid) * 4);
      am = fmaxf(am, fmaxf(fmaxf(fabsf(v[it].x), fabsf(v[it].y)), fmaxf(fabsf(v[it].z), fabsf(v[it].w))));
    }
    const float bm = blockMax256(am, r4);
#pragma unroll
    for (int it = 0; it < 2; ++it) {
      const int i = (it * 256 + tid) * 4;
      short4 hh, ll;
      unsigned hb;
      hb = bfr(v[it].x); hh.x = (short)hb; ll.x = (short)bfr(v[it].x - bf2f(hb));
      hb = bfr(v[it].y); hh.y = (short)hb; ll.y = (short)bfr(v[it].y - bf2f(hb));
      hb = bfr(v[it].z); hh.z = (short)hb; ll.z = (short)bfr(v[it].z - bf2f(hb));
      hb = bfr(v[it].w); hh.w = (short)hb; ll.w = (short)bfr(v[it].w - bf2f(hb));
      *reinterpret_cast<short4*>(khi + (size_t)row * kE + i) = hh;
      *reinterpret_cast<short4*>(klo + (size_t)row * kE + i) = ll;
    }
    if (tid == 0) {
      s4[row] = fmaxf(bm, 1e-5f) / 7.f;
      if (row < kT) smix[row] = fmaxf(bm / 127.f, 1e-5f);
    }
  }

  // ---- v absmax ----
  {
    const float* x = Vb + (size_t)row * kE;
    float am = 0.f;
#pragma unroll
    for (int it = 0; it < 2; ++it) {
      const float4 v = *reinterpret_cast<const float4*>(x + (size_t)(it * 256 + tid) * 4);
      am = fmaxf(am, fmaxf(fmaxf(fabsf(v.x), fabsf(v.y)), fmaxf(fabsf(v.z), fabsf(v.w))));
    }
    const float bm = blockMax256(am, r4);
    if (tid == 0) atomicMax(vmax, __float_as_uint(bm));
  }
}

// k fp32 -> mixed-quant int codes as bf16 + chosen scale per row
__global__ __launch_bounds__(256) void k_kint(const float* __restrict__ Kb,
                                              const float* __restrict__ s4,
                                              const float* __restrict__ smix,
                                              const int* __restrict__ sel,
                                              short* __restrict__ ki,
                                              float* __restrict__ skg) {
  const int row = blockIdx.x;
  const int tid = threadIdx.x;
  const int t = row & (kT - 1);
  const float s = sel[t] ? smix[t] : s4[row];
  const float* x = Kb + (size_t)row * kE;
#pragma unroll
  for (int it = 0; it < 2; ++it) {
    const int i = (it * 256 + tid) * 4;
    const float4 v = *reinterpret_cast<const float4*>(x + i);
    short4 q;
    q.x = (short)bfr(rintf(v.x / s));
    q.y = (short)bfr(rintf(v.y / s));
    q.z = (short)bfr(rintf(v.z / s));
    q.w = (short)bfr(rintf(v.w / s));
    *reinterpret_cast<short4*>(ki + (size_t)row * kE + i) = q;
  }
  if (tid == 0) skg[row] = s;
}

// v fp32 -> int codes as bf16, transposed per head: vt[(bh*64+d)*1024 + t]
__global__ __launch_bounds__(256) void k_vint(const float* __restrict__ Vb,
                                              const unsigned* __restrict__ vmax,
                                              short* __restrict__ vt) {
  const int tt = blockIdx.x;
  const int bh = blockIdx.y;
  const int b = bh >> 5, h = bh & 31;
  const float sv = fmaxf(__uint_as_float(*vmax), 1e-5f) / 7.f;
  __shared__ short tr[64][80];
  const int tid = threadIdx.x;
#pragma unroll
  for (int i = 0; i < 4; ++i) {
    const int e = i * 256 + tid;
    const int tok = e >> 4, d4 = (e & 15) * 4;
    const float4 v = *reinterpret_cast<const float4*>(
        &Vb[(size_t)(b * kT + tt * 64 + tok) * kE + h * 64 + d4]);
    tr[d4 + 0][tok] = (short)bfr(rintf(v.x / sv));
    tr[d4 + 1][tok] = (short)bfr(rintf(v.y / sv));
    tr[d4 + 2][tok] = (short)bfr(rintf(v.z / sv));
    tr[d4 + 3][tok] = (short)bfr(rintf(v.w / sv));
  }
  __syncthreads();
#pragma unroll
  for (int i = 0; i < 2; ++i) {
    const int e = i * 256 + tid;
    const int d = e >> 3, u = e & 7;
    const bf16x8 row = *reinterpret_cast<const bf16x8*>(&tr[d][u * 8]);
    *reinterpret_cast<bf16x8*>(&vt[(size_t)(bh * 64 + d) * kT + tt * 64 + u * 8]) = row;
  }
}

// ---------------- int8 MFMA GEMM (shared body; conflict-free LDS swizzle) ----------------
// swizzle key s(row) = (row>>1)&3: 16B-slot position (row&1)*4 + (g^s) covers all
// 8 bank-groups exactly twice per 16-lane read group -> 2-way aliasing (free).
__device__ __forceinline__ void gemm_i8_body(int m0, int n0,
                                             const int8_t* __restrict__ A,
                                             const float* __restrict__ sa,
                                             const int8_t* __restrict__ Bw,
                                             const float* __restrict__ sw,
                                             const float* __restrict__ bias,
                                             float* __restrict__ Y,
                                             int8_t* As0, int8_t* As1,
                                             int8_t* Bs0, int8_t* Bs1) {
  int8_t* Asb[2] = {As0, As1};
  int8_t* Bsb[2] = {Bs0, Bs1};
  const int tid = threadIdx.x;
  const int lane = tid & 63, w = tid >> 6;
  const int g = lane >> 4, c16 = lane & 15;
  const int wm = (w >> 1) * 64, wn = (w & 1) * 64;
  const int rsw = (c16 >> 1) & 3;  // read swizzle key

  const i32x4 zero = {0, 0, 0, 0};
  i32x4 acc[4][4];
#pragma unroll
  for (int i = 0; i < 4; ++i)
#pragma unroll
    for (int j = 0; j < 4; ++j) acc[i][j] = zero;

  const int srow = tid >> 2, su = tid & 3;
  const int ssw = (srow >> 1) & 3;  // stage swizzle key (row = i*64+srow, i*64 even mult of 8)
  auto stage = [&](int buf, int k0) {
#pragma unroll
    for (int i = 0; i < 2; ++i) {
      const int row = i * 64 + srow;
      const int uoff = ((su ^ ssw) << 4);  // pre-swizzled source -> swizzled LDS
      gload16(A + (size_t)(m0 + row) * kE + k0 + uoff, &Asb[buf][row * 64 + su * 16]);
      gload16(Bw + (size_t)(n0 + row) * kE + k0 + uoff, &Bsb[buf][row * 64 + su * 16]);
    }
  };

  stage(0, 0);
  __syncthreads();
  int cur = 0;
  for (int k0 = 0; k0 < kE; k0 += 64) {
    if (k0 + 64 < kE) stage(cur ^ 1, k0 + 64);
    i32x4 av[4], bv[4];
#pragma unroll
    for (int f = 0; f < 4; ++f) {
      const int ar = wm + f * 16 + c16;
      av[f] = *reinterpret_cast<const i32x4*>(&Asb[cur][ar * 64 + ((g ^ rsw) << 4)]);
      const int br = wn + f * 16 + c16;
      bv[f] = *reinterpret_cast<const i32x4*>(&Bsb[cur][br * 64 + ((g ^ rsw) << 4)]);
    }
#pragma unroll
    for (int fm = 0; fm < 4; ++fm)
#pragma unroll
      for (int fn = 0; fn < 4; ++fn) acc[fm][fn] = MFMA_I8(av[fm], bv[fn], acc[fm][fn]);
    __syncthreads();
    cur ^= 1;
  }

#pragma unroll
  for (int fn = 0; fn < 4; ++fn) {
    const int n = n0 + wn + fn * 16 + c16;
    const float swn = sw[n], bn = bias[n];
#pragma unroll
    for (int fm = 0; fm < 4; ++fm) {
#pragma unroll
      for (int r = 0; r < 4; ++r) {
        const int m = m0 + wm + fm * 16 + g * 4 + r;
        Y[(size_t)m * kE + n] = (float)acc[fm][fn][r] * sa[m] * swn + bn;
      }
    }
  }
}

// out-projection GEMM, grid (16,16); XCD-chunked remap (256 blocks = 32/XCD)
__global__ __launch_bounds__(256) void k_gemm_i8(const int8_t* __restrict__ A,
                                                 const float* __restrict__ sa,
                                                 const int8_t* __restrict__ Bw,
                                                 const float* __restrict__ sw,
                                                 const float* __restrict__ bias,
                                                 float* __restrict__ Y) {
  __shared__ int8_t As[2][128 * 64];
  __shared__ int8_t Bs[2][128 * 64];
  const int linear = blockIdx.x + (blockIdx.y << 4);
  const int nid = (linear & 7) * 32 + (linear >> 3);
  const int x = nid & 15, y = nid >> 4;
  gemm_i8_body(y * 128, x * 128, A, sa, Bw, sw, bias, Y, As[0], As[1], Bs[0], Bs[1]);
}

// fused Q/K/V projections, grid (16,16,3); XCD-chunked remap (768 blocks = 96/XCD)
__global__ __launch_bounds__(256) void k_gemm_qkv(const int8_t* __restrict__ A,
                                                  const float* __restrict__ sa,
                                                  const int8_t* __restrict__ Wq,
                                                  const int8_t* __restrict__ Wk,
                                                  const int8_t* __restrict__ Wv,
                                                  const float* __restrict__ sWall,
                                                  const float* __restrict__ bq,
                                                  const float* __restrict__ bk,
                                                  const float* __restrict__ bv,
                                                  float* __restrict__ qb,
                                                  float* __restrict__ kb,
                                                  float* __restrict__ vb) {
  __shared__ int8_t As[2][128 * 64];
  __shared__ int8_t Bs[2][128 * 64];
  const int linear = blockIdx.x + (blockIdx.y << 4) + (blockIdx.z << 8);
  const int nid = (linear & 7) * 96 + (linear >> 3);
  const int x = nid & 15, y = (nid >> 4) & 15, z = nid >> 8;
  const int8_t* Bw = (z == 0) ? Wq : (z == 1) ? Wk : Wv;
  const float* sw = sWall + (size_t)z * kE;
  const float* bias = (z == 0) ? bq : (z == 1) ? bk : bv;
  float* Y = (z == 0) ? qb : (z == 1) ? kb : vb;
  gemm_i8_body(y * 128, x * 128, A, sa, Bw, sw, bias, Y, As[0], As[1], Bs[0], Bs[1]);
}

// ---------------- attention pass 1 (paired q-tiles r1 and 15-r1) ----------------
__global__ __launch_bounds__(256) void k_attn1(const short* __restrict__ qi,
                                               const short* __restrict__ khi,
                                               const short* __restrict__ klo,
                                               const float* __restrict__ sqg,
                                               float* __restrict__ accPart) {
  const int r1 = blockIdx.x, r2 = 15 - r1, bh = blockIdx.y;
  const int b = bh >> 5, h = bh & 31;
  const int tid = threadIdx.x, lane = tid & 63, w = tid >> 6;
  const int g = lane >> 4, c16 = lane & 15;
  const int swz = c16 & 7;

  __shared__ short qs1[64 * 64];
  __shared__ short qs2[64 * 64];
  __shared__ short hbuf[2][64 * 64];
  __shared__ short lbuf[2][64 * 64];
  __shared__ float accL[1024];
  __shared__ float Arow[128], Crow[128];

  for (int i = tid; i < 1024; i += 256) accL[i] = 0.f;

  const int st8 = tid >> 3, su = tid & 7;
  {
    const int tokb1 = b * kT + r1 * 64;
    const int tokb2 = b * kT + r2 * 64;
#pragma unroll
    for (int i = 0; i < 2; ++i) {
      const int tok = i * 32 + st8;
      const int co = ((su ^ (tok & 7)) << 3);
      gload16(qi + (size_t)(tokb1 + tok) * kE + h * 64 + co, &qs1[tok * 64 + su * 8]);
      gload16(qi + (size_t)(tokb2 + tok) * kE + h * 64 + co, &qs2[tok * 64 + su * 8]);
    }
  }
  auto stage = [&](int buf, int kt) {
    const int tokb = b * kT + kt * 64;
#pragma unroll
    for (int i = 0; i < 2; ++i) {
      const int tok = i * 32 + st8;
      const size_t gsrc = (size_t)(tokb + tok) * kE + h * 64 + ((su ^ (tok & 7)) << 3);
      gload16(khi + gsrc, &hbuf[buf][tok * 64 + su * 8]);
      gload16(klo + gsrc, &lbuf[buf][tok * 64 + su * 8]);
    }
  };

  stage(0, 0);
  __syncthreads();

  // ---- phase A: row stats for both q-tiles (S^T = K*Q) ----
  const int qrow = w * 16 + c16;
  const bf16x8 q1_0 = *reinterpret_cast<const bf16x8*>(&qs1[qrow * 64 + ((g ^ swz) << 3)]);
  const bf16x8 q1_1 = *reinterpret_cast<const bf16x8*>(&qs1[qrow * 64 + (((4 + g) ^ swz) << 3)]);
  const bf16x8 q2_0 = *reinterpret_cast<const bf16x8*>(&qs2[qrow * 64 + ((g ^ swz) << 3)]);
  const bf16x8 q2_1 = *reinterpret_cast<const bf16x8*>(&qs2[qrow * 64 + (((4 + g) ^ swz) << 3)]);
  const float A1c = sqg[b * kT + r1 * 64 + qrow] * L2E;
  const float A2c = sqg[b * kT + r2 * 64 + qrow] * L2E;

  float m1 = NEG_INF, l1 = 0.f, m2_ = NEG_INF, l2 = 0.f;
  int cur = 0;

  for (int kt = 0; kt <= r2; ++kt) {
    if (kt < r2) stage(cur ^ 1, kt + 1);
    const bool act1 = kt <= r1;
    float p1[4][4], p2[4][4];
    float pm1 = NEG_INF, pm2 = NEG_INF;
#pragma unroll
    for (int f = 0; f < 4; ++f) {
      const int tokl = f * 16 + c16;
      const bf16x8 ah0 = *reinterpret_cast<const bf16x8*>(&hbuf[cur][tokl * 64 + ((g ^ swz) << 3)]);
      const bf16x8 ah1 = *reinterpret_cast<const bf16x8*>(&hbuf[cur][tokl * 64 + (((4 + g) ^ swz) << 3)]);
      const bf16x8 al0 = *reinterpret_cast<const bf16x8*>(&lbuf[cur][tokl * 64 + ((g ^ swz) << 3)]);
      const bf16x8 al1 = *reinterpret_cast<const bf16x8*>(&lbuf[cur][tokl * 64 + (((4 + g) ^ swz) << 3)]);
      f32x4 sB = {0.f, 0.f, 0.f, 0.f};
      sB = MFMA_BF16(ah0, q2_0, sB);
      sB = MFMA_BF16(ah1, q2_1, sB);
      sB = MFMA_BF16(al0, q2_0, sB);
      sB = MFMA_BF16(al1, q2_1, sB);
      f32x4 sA = {0.f, 0.f, 0.f, 0.f};
      if (act1) {
        sA = MFMA_BF16(ah0, q1_0, sA);
        sA = MFMA_BF16(ah1, q1_1, sA);
        sA = MFMA_BF16(al0, q1_0, sA);
        sA = MFMA_BF16(al1, q1_1, sA);
      }
#pragma unroll
      for (int r = 0; r < 4; ++r) {
        const int tokd = f * 16 + g * 4 + r;
        float s2 = sB[r] * A2c;
        if (kt == r2 && tokd > qrow) s2 = NEG_INF;
        p2[f][r] = s2;
        pm2 = fmaxf(pm2, s2);
        float s1 = sA[r] * A1c;
        if (kt == r1 && tokd > qrow) s1 = NEG_INF;
        p1[f][r] = s1;
        pm1 = fmaxf(pm1, s1);
      }
    }
    {
      pm2 = fmaxf(pm2, __shfl_xor(pm2, 16));
      pm2 = fmaxf(pm2, __shfl_xor(pm2, 32));
      const bool upd = pm2 > m2_ + 8.f;
      const float mn = upd ? fmaxf(m2_, pm2) : m2_;
      const float fsc = fexp2(m2_ - mn);
      float rs = 0.f;
#pragma unroll
      for (int f = 0; f < 4; ++f)
#pragma unroll
        for (int r = 0; r < 4; ++r) rs += fexp2(p2[f][r] - mn);
      rs += __shfl_xor(rs, 16);
      rs += __shfl_xor(rs, 32);
      l2 = l2 * fsc + rs;
      m2_ = mn;
    }
    if (act1) {
      pm1 = fmaxf(pm1, __shfl_xor(pm1, 16));
      pm1 = fmaxf(pm1, __shfl_xor(pm1, 32));
      const bool upd = pm1 > m1 + 8.f;
      const float mn = upd ? fmaxf(m1, pm1) : m1;
      const float fsc = fexp2(m1 - mn);
      float rs = 0.f;
#pragma unroll
      for (int f = 0; f < 4; ++f)
#pragma unroll
        for (int r = 0; r < 4; ++r) rs += fexp2(p1[f][r] - mn);
      rs += __shfl_xor(rs, 16);
      rs += __shfl_xor(rs, 32);
      l1 = l1 * fsc + rs;
      m1 = mn;
    }
    __syncthreads();
    cur ^= 1;
  }

  if (g == 0) {
    Arow[qrow] = A1c;
    Crow[qrow] = -(m1 + __builtin_amdgcn_logf(l1));
    Arow[64 + qrow] = A2c;
    Crow[64 + qrow] = -(m2_ + __builtin_amdgcn_logf(l2));
  }
  stage(0, 0);
  __syncthreads();

  // ---- phase B: normalized column sums (S = Q*K), both q-tiles ----
  bf16x8 qa1_0[4], qa1_1[4], qa2_0[4], qa2_1[4];
  float Ar1[4][4], Cr1[4][4], Ar2[4][4], Cr2[4][4];
#pragma unroll
  for (int f = 0; f < 4; ++f) {
    const int qr = f * 16 + c16;
    qa1_0[f] = *reinterpret_cast<const bf16x8*>(&qs1[qr * 64 + ((g ^ swz) << 3)]);
    qa1_1[f] = *reinterpret_cast<const bf16x8*>(&qs1[qr * 64 + (((4 + g) ^ swz) << 3)]);
    qa2_0[f] = *reinterpret_cast<const bf16x8*>(&qs2[qr * 64 + ((g ^ swz) << 3)]);
    qa2_1[f] = *reinterpret_cast<const bf16x8*>(&qs2[qr * 64 + (((4 + g) ^ swz) << 3)]);
#pragma unroll
    for (int r = 0; r < 4; ++r) {
      const int tokd = f * 16 + g * 4 + r;
      Ar1[f][r] = Arow[tokd];
      Cr1[f][r] = Crow[tokd];
      Ar2[f][r] = Arow[64 + tokd];
      Cr2[f][r] = Crow[64 + tokd];
    }
  }

  const int ktokL = w * 16 + c16;
  cur = 0;
  for (int kt = 0; kt <= r2; ++kt) {
    if (kt < r2) stage(cur ^ 1, kt + 1);
    const bf16x8 kh0 = *reinterpret_cast<const bf16x8*>(&hbuf[cur][ktokL * 64 + ((g ^ swz) << 3)]);
    const bf16x8 kh1 = *reinterpret_cast<const bf16x8*>(&hbuf[cur][ktokL * 64 + (((4 + g) ^ swz) << 3)]);
    const bf16x8 kl0 = *reinterpret_cast<const bf16x8*>(&lbuf[cur][ktokL * 64 + ((g ^ swz) << 3)]);
    const bf16x8 kl1 = *reinterpret_cast<const bf16x8*>(&lbuf[cur][ktokL * 64 + (((4 + g) ^ swz) << 3)]);
    float csum = 0.f;
    if (kt < r2) {
#pragma unroll
      for (int f = 0; f < 4; ++f) {
        f32x4 sf = {0.f, 0.f, 0.f, 0.f};
        sf = MFMA_BF16(qa2_0[f], kh0, sf);
        sf = MFMA_BF16(qa2_1[f], kh1, sf);
        sf = MFMA_BF16(qa2_0[f], kl0, sf);
        sf = MFMA_BF16(qa2_1[f], kl1, sf);
#pragma unroll
        for (int r = 0; r < 4; ++r) csum += fexp2(fmaf(sf[r], Ar2[f][r], Cr2[f][r]));
      }
    } else {
#pragma unroll
      for (int f = 0; f < 4; ++f) {
        f32x4 sf = {0.f, 0.f, 0.f, 0.f};
        sf = MFMA_BF16(qa2_0[f], kh0, sf);
        sf = MFMA_BF16(qa2_1[f], kh1, sf);
        sf = MFMA_BF16(qa2_0[f], kl0, sf);
        sf = MFMA_BF16(qa2_1[f], kl1, sf);
#pragma unroll
        for (int r = 0; r < 4; ++r) {
          const float v = fexp2(fmaf(sf[r], Ar2[f][r], Cr2[f][r]));
          if (ktokL <= (f * 16 + g * 4 + r)) csum += v;
        }
      }
    }
    if (kt <= r1) {
      if (kt < r1) {
#pragma unroll
        for (int f = 0; f < 4; ++f) {
          f32x4 sf = {0.f, 0.f, 0.f, 0.f};
          sf = MFMA_BF16(qa1_0[f], kh0, sf);
          sf = MFMA_BF16(qa1_1[f], kh1, sf);
          sf = MFMA_BF16(qa1_0[f], kl0, sf);
          sf = MFMA_BF16(qa1_1[f], kl1, sf);
#pragma unroll
          for (int r = 0; r < 4; ++r) csum += fexp2(fmaf(sf[r], Ar1[f][r], Cr1[f][r]));
        }
      } else {
#pragma unroll
        for (int f = 0; f < 4; ++f) {
          f32x4 sf = {0.f, 0.f, 0.f, 0.f};
          sf = MFMA_BF16(qa1_0[f], kh0, sf);
          sf = MFMA_BF16(qa1_1[f], kh1, sf);
          sf = MFMA_BF16(qa1_0[f], kl0, sf);
          sf = MFMA_BF16(qa1_1[f], kl1, sf);
#pragma unroll
          for (int r = 0; r < 4; ++r) {
            const float v = fexp2(fmaf(sf[r], Ar1[f][r], Cr1[f][r]));
            if (ktokL <= (f * 16 + g * 4 + r)) csum += v;
          }
        }
      }
    }
    csum += __shfl_xor(csum, 16);
    csum += __shfl_xor(csum, 32);
    if (g == 0) accL[kt * 64 + ktokL] += csum;
    __syncthreads();
    cur ^= 1;
  }

  for (int i = tid; i < 1024; i += 256)
    accPart[(size_t)(bh * 8 + r1) * 1024 + i] = accL[i];
}

__global__ __launch_bounds__(256) void k_accreduce(const float* __restrict__ part,
                                                   float* __restrict__ acc) {
  const int j = blockIdx.x;
  const int tid = threadIdx.x;
  float s = 0.f;
  for (int p = tid; p < 512; p += 256) s += part[(size_t)p * 1024 + j];
  __shared__ float r4[4];
  const float ws = waveReduceSum(s);
  if ((tid & 63) == 0) r4[tid >> 6] = ws;
  __syncthreads();
  if (tid == 0) {
    const float t = r4[0] + r4[1] + r4[2] + r4[3];
    acc[j] = t / (float)(kT - j) / 64.f;
  }
}

__global__ __launch_bounds__(256) void k_topk(const float* __restrict__ acc,
                                              int* __restrict__ sel) {
  const int gq = blockIdx.x;
  const int i = threadIdx.x;
  __shared__ float v[256];
  const float vi = acc[gq * 256 + i];
  v[i] = vi;
  __syncthreads();
  int rank = 0;
  for (int j = 0; j < 256; ++j) {
    const float vj = v[j];
    rank += (vj > vi) || (vj == vi && j < i);
  }
  sel[gq * 256 + i] = (rank < 128) ? 1 : 0;
}

// ---------------- attention pass 2 (paired flash, single-bf16 P) ----------------
__global__ __launch_bounds__(256) void k_attn2(const short* __restrict__ qi,
                                               const short* __restrict__ ki,
                                               const short* __restrict__ vt,
                                               const float* __restrict__ sqg,
                                               const float* __restrict__ skg,
                                               const unsigned* __restrict__ vmax,
                                               float* __restrict__ ctx) {
  const int r1 = blockIdx.x, r2 = 15 - r1, bh = blockIdx.y;
  const int b = bh >> 5, h = bh & 31;
  const int tid = threadIdx.x, lane = tid & 63, w = tid >> 6;
  const int g = lane >> 4, c16 = lane & 15;
  const int swz = c16 & 7;
  const int wrow = w * 16 + c16;

  __shared__ short kbuf[2][64 * 64];
  __shared__ short vbuf[2][64 * 64];
  __shared__ float skl[2][64];

  const int qtokA = b * kT + r1 * 64 + wrow;
  const int qtokB = b * kT + r2 * 64 + wrow;
  bf16x8 qfA[2], qfB[2];
  qfA[0] = *reinterpret_cast<const bf16x8*>(qi + (size_t)qtokA * kE + h * 64 + g * 8);
  qfA[1] = *reinterpret_cast<const bf16x8*>(qi + (size_t)qtokA * kE + h * 64 + 32 + g * 8);
  qfB[0] = *reinterpret_cast<const bf16x8*>(qi + (size_t)qtokB * kE + h * 64 + g * 8);
  qfB[1] = *reinterpret_cast<const bf16x8*>(qi + (size_t)qtokB * kE + h * 64 + 32 + g * 8);
  const float sqA = sqg[qtokA] * L2E;
  const float sqB = sqg[qtokB] * L2E;
  const float sv = fmaxf(__uint_as_float(*vmax), 1e-5f) / 7.f;

  const int st8 = tid >> 3, su = tid & 7;
  auto stage = [&](int buf, int kt) {
    const int tokb = b * kT + kt * 64;
#pragma unroll
    for (int i = 0; i < 2; ++i) {
      const int tok = i * 32 + st8;
      gload16(ki + (size_t)(tokb + tok) * kE + h * 64 + ((su ^ (tok & 7)) << 3),
              &kbuf[buf][tok * 64 + su * 8]);
      gload16(vt + (size_t)(bh * 64 + tok) * kT + kt * 64 + ((su ^ (tok & 7)) << 3),
              &vbuf[buf][tok * 64 + su * 8]);
    }
    if (tid < 64) skl[buf][tid] = skg[tokb + tid];
  };

  float mA = NEG_INF, lA = 0.f, mB = NEG_INF, lB = 0.f;
  f32x4 otA[4], otB[4];
#pragma unroll
  for (int f = 0; f < 4; ++f) {
    otA[f] = (f32x4){0.f, 0.f, 0.f, 0.f};
    otB[f] = (f32x4){0.f, 0.f, 0.f, 0.f};
  }

  stage(0, 0);
  __syncthreads();
  int cur = 0;

  const int srcLo = c16 | ((g & 1) << 5);
  const int srcHi = srcLo | 16;
  const bool selq = ((g >> 1) & 1) != 0;

  for (int kt = 0; kt <= r2; ++kt) {
    if (kt < r2) stage(cur ^ 1, kt + 1);
    const bool act1 = kt <= r1;

    f32x4 sfB4[4], sfA4[4];
#pragma unroll
    for (int f = 0; f < 4; ++f) {
      const int tokl = f * 16 + c16;
      const bf16x8 k0 = *reinterpret_cast<const bf16x8*>(&kbuf[cur][tokl * 64 + ((g ^ swz) << 3)]);
      const bf16x8 k1 = *reinterpret_cast<const bf16x8*>(&kbuf[cur][tokl * 64 + (((4 + g) ^ swz) << 3)]);
      f32x4 s = {0.f, 0.f, 0.f, 0.f};
      s = MFMA_BF16(k0, qfB[0], s);
      s = MFMA_BF16(k1, qfB[1], s);
      sfB4[f] = s;
      f32x4 sa = {0.f, 0.f, 0.f, 0.f};
      if (act1) {
        sa = MFMA_BF16(k0, qfA[0], sa);
        sa = MFMA_BF16(k1, qfA[1], sa);
      }
      sfA4[f] = sa;
    }

    // ---- tile B softmax + PV ----
    {
      float p[4][4];
      float pm = NEG_INF;
#pragma unroll
      for (int f = 0; f < 4; ++f)
#pragma unroll
        for (int r = 0; r < 4; ++r) {
          const int tokd = f * 16 + g * 4 + r;
          float s2 = sfB4[f][r] * skl[cur][tokd] * sqB;
          if (kt == r2 && tokd > wrow) s2 = NEG_INF;
          p[f][r] = s2;
          pm = fmaxf(pm, s2);
        }
      pm = fmaxf(pm, __shfl_xor(pm, 16));
      pm = fmaxf(pm, __shfl_xor(pm, 32));
      const bool upd = pm > mB + 8.f;
      const float mn = upd ? fmaxf(mB, pm) : mB;
      const float fsc = fexp2(mB - mn);
      mB = mn;
      float rs = 0.f;
#pragma unroll
      for (int f = 0; f < 4; ++f)
#pragma unroll
        for (int r = 0; r < 4; ++r) {
          const float e = fexp2(p[f][r] - mn);
          p[f][r] = e;
          rs += e;
        }
      rs += __shfl_xor(rs, 16);
      rs += __shfl_xor(rs, 32);
      lB = lB * fsc + rs;
      if (__any(upd)) {
#pragma unroll
        for (int f = 0; f < 4; ++f)
#pragma unroll
          for (int r = 0; r < 4; ++r) otB[f][r] *= fsc;
      }
#pragma unroll
      for (int c = 0; c < 2; ++c) {
        const unsigned q0a = pk2(p[2 * c][0], p[2 * c][1]);
        const unsigned q0b = pk2(p[2 * c][2], p[2 * c][3]);
        const unsigned q1a = pk2(p[2 * c + 1][0], p[2 * c + 1][1]);
        const unsigned q1b = pk2(p[2 * c + 1][2], p[2 * c + 1][3]);
        unsigned a0, a1;
        union { unsigned u[4]; bf16x8 v; } Bh;
        a0 = __shfl(q0a, srcLo); a1 = __shfl(q1a, srcLo); Bh.u[0] = selq ? a1 : a0;
        a0 = __shfl(q0b, srcLo); a1 = __shfl(q1b, srcLo); Bh.u[1] = selq ? a1 : a0;
        a0 = __shfl(q0a, srcHi); a1 = __shfl(q1a, srcHi); Bh.u[2] = selq ? a1 : a0;
        a0 = __shfl(q0b, srcHi); a1 = __shfl(q1b, srcHi); Bh.u[3] = selq ? a1 : a0;
#pragma unroll
        for (int fd = 0; fd < 4; ++fd) {
          const int d = fd * 16 + c16;
          const bf16x8 va = *reinterpret_cast<const bf16x8*>(
              &vbuf[cur][d * 64 + ((((c << 2) | g) ^ swz) << 3)]);
          otB[fd] = MFMA_BF16(va, Bh.v, otB[fd]);
        }
      }
    }

    // ---- tile A softmax + PV (gated) ----
    if (act1) {
      float p[4][4];
      float pm = NEG_INF;
#pragma unroll
      for (int f = 0; f < 4; ++f)
#pragma unroll
        for (int r = 0; r < 4; ++r) {
          const int tokd = f * 16 + g * 4 + r;
          float s2 = sfA4[f][r] * skl[cur][tokd] * sqA;
          if (kt == r1 && tokd > wrow) s2 = NEG_INF;
          p[f][r] = s2;
          pm = fmaxf(pm, s2);
        }
      pm = fmaxf(pm, __shfl_xor(pm, 16));
      pm = fmaxf(pm, __shfl_xor(pm, 32));
      const bool upd = pm > mA + 8.f;
      const float mn = upd ? fmaxf(mA, pm) : mA;
      const float fsc = fexp2(mA - mn);
      mA = mn;
      float rs = 0.f;
#pragma unroll
      for (int f = 0; f < 4; ++f)
#pragma unroll
        for (int r = 0; r < 4; ++r) {
          const float e = fexp2(p[f][r] - mn);
          p[f][r] = e;
          rs += e;
        }
      rs += __shfl_xor(rs, 16);
      rs += __shfl_xor(rs, 32);
      lA = lA * fsc + rs;
      if (__any(upd)) {
#pragma unroll
        for (int f = 0; f < 4; ++f)
#pragma unroll
          for (int r = 0; r < 4; ++r) otA[f][r] *= fsc;
      }
#pragma unroll
      for (int c = 0; c < 2; ++c) {
        const unsigned q0a = pk2(p[2 * c][0], p[2 * c][1]);
        const unsigned q0b = pk2(p[2 * c][2], p[2 * c][3]);
        const unsigned q1a = pk2(p[2 * c + 1][0], p[2 * c + 1][1]);
        const unsigned q1b = pk2(p[2 * c + 1][2], p[2 * c + 1][3]);
        unsigned a0, a1;
        union { unsigned u[4]; bf16x8 v; } Bh;
        a0 = __shfl(q0a, srcLo); a1 = __shfl(q1a, srcLo); Bh.u[0] = selq ? a1 : a0;
        a0 = __shfl(q0b, srcLo); a1 = __shfl(q1b, srcLo); Bh.u[1] = selq ? a1 : a0;
        a0 = __shfl(q0a, srcHi); a1 = __shfl(q1a, srcHi); Bh.u[2] = selq ? a1 : a0;
        a0 = __shfl(q0b, srcHi); a1 = __shfl(q1b, srcHi); Bh.u[3] = selq ? a1 : a0;
#pragma unroll
        for (int fd = 0; fd < 4; ++fd) {
          const int d = fd * 16 + c16;
          const bf16x8 va = *reinterpret_cast<const bf16x8*>(
              &vbuf[cur][d * 64 + ((((c << 2) | g) ^ swz) << 3)]);
          otA[fd] = MFMA_BF16(va, Bh.v, otA[fd]);
        }
      }
    }

    __syncthreads();
    cur ^= 1;
  }

  const float ilA = sv / lA;
  const float ilB = sv / lB;
#pragma unroll
  for (int fd = 0; fd < 4; ++fd) {
    float4 oA, oB;
    oA.x = otA[fd][0] * ilA; oA.y = otA[fd][1] * ilA;
    oA.z = otA[fd][2] * ilA; oA.w = otA[fd][3] * ilA;
    oB.x = otB[fd][0] * ilB; oB.y = otB[fd][1] * ilB;
    oB.z = otB[fd][2] * ilB; oB.w = otB[fd][3] * ilB;
    *reinterpret_cast<float4*>(&ctx[(size_t)qtokA * kE + h * 64 + fd * 16 + g * 4]) = oA;
    *reinterpret_cast<float4*>(&ctx[(size_t)qtokB * kE + h * 64 + fd * 16 + g * 4]) = oB;
  }
}

// ---------------- launcher ----------------
extern "C" void kernel_launch(void* const* d_in, const int* in_sizes, int n_in,
                              void* d_out, int out_size, void* d_ws, size_t ws_size,
                              hipStream_t stream) {
  (void)in_sizes; (void)n_in; (void)out_size; (void)ws_size;
  const float* hs = (const float*)d_in[0];
  const float* Wq = (const float*)d_in[2];
  const float* bq = (const float*)d_in[3];
  const float* Wk = (const float*)d_in[4];
  const float* bk = (const float*)d_in[5];
  const float* Wv = (const float*)d_in[6];
  const float* bv = (const float*)d_in[7];
  const float* Wo = (const float*)d_in[8];
  const float* bo = (const float*)d_in[9];
  float* out = (float*)d_out;

  char* p = (char*)d_ws;
  auto take = [&](size_t bytes) {
    char* r = p;
    p += (bytes + 255) & ~(size_t)255;
    return r;
  };
  float* qb  = (float*)take((size_t)2048 * 2048 * 4);  // later khi+klo -> kint+vt
  float* kb  = (float*)take((size_t)2048 * 2048 * 4);
  float* vb  = (float*)take((size_t)2048 * 2048 * 4);
  float* ctx = (float*)take((size_t)2048 * 2048 * 4);  // accPart(2MB) + wq/wk/wv(12MB) alias
  short* qiB = (short*)take((size_t)2048 * 2048 * 2);
  int8_t* xq  = (int8_t*)take((size_t)2048 * 2048);
  int8_t* woq = (int8_t*)take((size_t)2048 * 2048);
  float* sX    = (float*)take(2048 * 4);
  float* sWall = (float*)take(4 * 2048 * 4);
  float* sC    = (float*)take(2048 * 4);
  float* s4v   = (float*)take(2048 * 4);
  float* smix  = (float*)take(1024 * 4);
  float* accv  = (float*)take(1024 * 4);
  int*   sel   = (int*)take(1024 * 4);
  float* sqg   = (float*)take(2048 * 4);
  float* skg   = (float*)take(2048 * 4);
  unsigned* vmax = (unsigned*)take(256);

  // aliases
  short* khi = (short*)qb;
  short* klo = (short*)qb + (size_t)2048 * 2048;
  short* kint = khi;
  short* vtp  = klo;
  float* accPart = ctx;                                  // 512*1024*4 = 2MB
  int8_t* wqq = (int8_t*)ctx + ((size_t)2 << 20);        // weights parked in ctx region
  int8_t* wkq = (int8_t*)ctx + ((size_t)6 << 20);
  int8_t* wvq = (int8_t*)ctx + ((size_t)10 << 20);
  int8_t* cq = xq;

  k_rowquant_all<<<dim3(2048, 5), 256, 0, stream>>>(hs, Wq, Wk, Wv, Wo,
                                                    xq, wqq, wkq, wvq, woq,
                                                    sX, sWall, vmax);

  k_gemm_qkv<<<dim3(16, 16, 3), 256, 0, stream>>>(xq, sX, wqq, wkq, wvq, sWall,
                                                  bq, bk, bv, qb, kb, vb);

  k_prep<<<2048, 256, 0, stream>>>(qb, kb, vb, qiB, sqg, khi, klo, s4v, smix, vmax);

  k_attn1<<<dim3(8, 64), 256, 0, stream>>>(qiB, khi, klo, sqg, accPart);
  k_accreduce<<<1024, 256, 0, stream>>>(accPart, accv);
  k_topk<<<4, 256, 0, stream>>>(accv, sel);

  k_kint<<<2048, 256, 0, stream>>>(kb, s4v, smix, sel, kint, skg);
  k_vint<<<dim3(16, 64), 256, 0, stream>>>(vb, vmax, vtp);

  k_attn2<<<dim3(8, 64), 256, 0, stream>>>(qiB, kint, vtp, sqg, skg, vmax, ctx);

  k_rowquant_i8<<<2048, 256, 0, stream>>>(ctx, cq, sC);
  k_gemm_i8<<<dim3(16, 16), 256, 0, stream>>>(cq, sC, woq, sWall + 3 * 2048, bo, out);
}